// Round 1
// baseline (954.676 us; speedup 1.0000x reference)
//
#include <hip/hip_runtime.h>
#include <cmath>

#define ROWS 4096      // B*N
#define DIM 768        // D
#define QKV_COLS 2304  // 3*D
#define NHEAD 12
#define HEAD_DIM 64
#define SEQ 2048

static constexpr float SCALE_F = 0.125f;   // HD^-0.5
static constexpr float EPS_F   = 1e-8f;

__device__ __forceinline__ float wave_sum64(float v) {
#pragma unroll
  for (int off = 1; off < 64; off <<= 1) v += __shfl_xor(v, off, 64);
  return v;
}

// ---------------- log0: v = artanh(min(sc*n,1-1e-7)) * x / (sc*n) ----------------
__global__ __launch_bounds__(256) void log0_kernel(const float* __restrict__ x,
                                                   const float* __restrict__ cptr,
                                                   float* __restrict__ vout) {
  const int lane = threadIdx.x & 63;
  const int row  = (blockIdx.x << 2) + (threadIdx.x >> 6);
  const float* xr = x + (size_t)row * DIM;
  float* vr = vout + (size_t)row * DIM;
  float vals[12];
  float ss = 0.f;
#pragma unroll
  for (int i = 0; i < 12; ++i) {
    float t = xr[lane + (i << 6)];
    vals[i] = t;
    ss += t * t;
  }
  ss = wave_sum64(ss);
  const float sc  = sqrtf(cptr[0]);
  const float n   = fmaxf(sqrtf(ss), EPS_F);
  const float scn = sc * n;
  const float t   = fminf(scn, 1.0f - 1e-7f);
  const float f   = atanhf(t) / scn;
#pragma unroll
  for (int i = 0; i < 12; ++i) vr[lane + (i << 6)] = vals[i] * f;
}

// ---------------- final exp0: out = tanh(sc*n) * v / (sc*n) ----------------
__global__ __launch_bounds__(256) void exp0_out_kernel(const float* __restrict__ vin,
                                                       const float* __restrict__ cptr,
                                                       float* __restrict__ outp) {
  const int lane = threadIdx.x & 63;
  const int row  = (blockIdx.x << 2) + (threadIdx.x >> 6);
  const float* vr = vin + (size_t)row * DIM;
  float* orow = outp + (size_t)row * DIM;
  float vals[12];
  float ss = 0.f;
#pragma unroll
  for (int i = 0; i < 12; ++i) {
    float t = vr[lane + (i << 6)];
    vals[i] = t;
    ss += t * t;
  }
  ss = wave_sum64(ss);
  const float sc  = sqrtf(cptr[0]);
  const float n   = fmaxf(sqrtf(ss), EPS_F);
  const float scn = sc * n;
  const float f   = tanhf(scn) / scn;
#pragma unroll
  for (int i = 0; i < 12; ++i) orow[lane + (i << 6)] = vals[i] * f;
}

// ---------------- SGEMM NT: C[M,Nc] = A[M,K] * B[Nc,K]^T (+bias) ----------------
// 128x128 tile, BK=8, 256 threads, 8x8 micro-tile (split 4+4 to keep LDS reads 2-way max)
__global__ __launch_bounds__(256) void sgemm_nt(const float* __restrict__ A,
                                                const float* __restrict__ Bm,
                                                float* __restrict__ C,
                                                int M, int Ncols, int K,
                                                const float* __restrict__ bias) {
  __shared__ float As[8][132];
  __shared__ float Bs[8][132];
  const int tid  = threadIdx.x;
  const int brow = blockIdx.y << 7;
  const int bcol = blockIdx.x << 7;
  const int tx = tid & 15, ty = tid >> 4;
  const int ldr = tid >> 1;          // 0..127
  const int ldk = (tid & 1) << 2;    // 0 or 4
  const float* Ap = A + (size_t)(brow + ldr) * K + ldk;
  const float* Bp = Bm + (size_t)(bcol + ldr) * K + ldk;
  float acc[8][8];
#pragma unroll
  for (int i = 0; i < 8; ++i)
#pragma unroll
    for (int j = 0; j < 8; ++j) acc[i][j] = 0.f;

  for (int k0 = 0; k0 < K; k0 += 8) {
    const float4 av = *(const float4*)(Ap + k0);
    const float4 bv = *(const float4*)(Bp + k0);
    __syncthreads();
    As[ldk + 0][ldr] = av.x; As[ldk + 1][ldr] = av.y;
    As[ldk + 2][ldr] = av.z; As[ldk + 3][ldr] = av.w;
    Bs[ldk + 0][ldr] = bv.x; Bs[ldk + 1][ldr] = bv.y;
    Bs[ldk + 2][ldr] = bv.z; Bs[ldk + 3][ldr] = bv.w;
    __syncthreads();
#pragma unroll
    for (int kk = 0; kk < 8; ++kk) {
      const float4 a0 = *(const float4*)&As[kk][ty << 2];
      const float4 a1 = *(const float4*)&As[kk][64 + (ty << 2)];
      const float4 b0 = *(const float4*)&Bs[kk][tx << 2];
      const float4 b1 = *(const float4*)&Bs[kk][64 + (tx << 2)];
      const float a[8] = {a0.x, a0.y, a0.z, a0.w, a1.x, a1.y, a1.z, a1.w};
      const float bq[8] = {b0.x, b0.y, b0.z, b0.w, b1.x, b1.y, b1.z, b1.w};
#pragma unroll
      for (int i = 0; i < 8; ++i)
#pragma unroll
        for (int j = 0; j < 8; ++j) acc[i][j] = fmaf(a[i], bq[j], acc[i][j]);
    }
  }

  float bvals[8];
#pragma unroll
  for (int j = 0; j < 8; ++j) {
    const int c = (j < 4) ? (tx << 2) + j : 64 + (tx << 2) + (j - 4);
    bvals[j] = bias ? bias[bcol + c] : 0.0f;
  }
#pragma unroll
  for (int i = 0; i < 8; ++i) {
    const int r = brow + ((i < 4) ? (ty << 2) + i : 64 + (ty << 2) + (i - 4));
    float* Cp = C + (size_t)r * Ncols + bcol;
    float4 o0, o1;
    o0.x = acc[i][0] + bvals[0]; o0.y = acc[i][1] + bvals[1];
    o0.z = acc[i][2] + bvals[2]; o0.w = acc[i][3] + bvals[3];
    o1.x = acc[i][4] + bvals[4]; o1.y = acc[i][5] + bvals[5];
    o1.z = acc[i][6] + bvals[6]; o1.w = acc[i][7] + bvals[7];
    *(float4*)(Cp + (tx << 2)) = o0;
    *(float4*)(Cp + 64 + (tx << 2)) = o1;
  }
}

// ------------- exp0 applied in place to q,k slices of qkv + squared norms -------------
__global__ __launch_bounds__(256) void exp0_qk_kernel(float* __restrict__ qkv,
                                                      const float* __restrict__ cptr,
                                                      float* __restrict__ qn,
                                                      float* __restrict__ kn) {
  const int lane = threadIdx.x & 63;
  const int vec  = (blockIdx.x << 2) + (threadIdx.x >> 6); // 0..98303
  const int which = vec & 1;
  const int rest  = vec >> 1;
  const int h   = rest % NHEAD;
  const int row = rest / NHEAD;
  float* p = qkv + (size_t)row * QKV_COLS + which * DIM + h * HEAD_DIM + lane;
  const float t = p[0];
  const float ss = wave_sum64(t * t);
  const float sc  = sqrtf(cptr[0]);
  const float n   = fmaxf(sqrtf(ss), EPS_F);
  const float scn = sc * n;
  const float f   = tanhf(scn) / scn;
  const float m   = t * f;
  p[0] = m;
  const float ss2 = wave_sum64(m * m);
  if (lane == 0) {
    float* dst = which ? kn : qn;
    dst[(size_t)row * NHEAD + h] = ss2;
  }
}

// ------------- flash attention with hyperbolic-distance scores -------------
// one block = (b, h, 64-query tile); 256 threads as 16x16, 4x4 acc per thread
__global__ __launch_bounds__(256) void flash_kernel(const float* __restrict__ qkv,
                                                    const float* __restrict__ qn,
                                                    const float* __restrict__ kn,
                                                    float* __restrict__ attn_out) {
  const int qt = blockIdx.x;
  const int h  = blockIdx.y;
  const int b  = blockIdx.z;
  const int tid = threadIdx.x;
  const int tx = tid & 15, ty = tid >> 4;

  __shared__ float Qt[64][68];  // [hd][q]
  __shared__ float Kt[64][68];  // [hd][k]
  __shared__ float Vs[64][68];  // [k][hd]
  __shared__ float Ss[64][65];  // [q][k] scores -> probs
  __shared__ float qn_s[64], kn_s[64], m_s[64], l_s[64], al_s[64];

  const size_t qrow0 = (size_t)b * SEQ + (size_t)qt * 64;
  {
    const int i = tid >> 2, hd0 = (tid & 3) << 4;
    const float* src = qkv + (qrow0 + i) * QKV_COLS + h * HEAD_DIM + hd0;
#pragma unroll
    for (int z = 0; z < 16; z += 4) {
      const float4 v = *(const float4*)(src + z);
      Qt[hd0 + z + 0][i] = v.x;
      Qt[hd0 + z + 1][i] = v.y;
      Qt[hd0 + z + 2][i] = v.z;
      Qt[hd0 + z + 3][i] = v.w;
    }
  }
  if (tid < 64) {
    qn_s[tid] = qn[(qrow0 + tid) * NHEAD + h];
    m_s[tid] = -INFINITY;
    l_s[tid] = 0.0f;
  }
  float acc[4][4];
#pragma unroll
  for (int i = 0; i < 4; ++i)
#pragma unroll
    for (int j = 0; j < 4; ++j) acc[i][j] = 0.f;

  for (int kt = 0; kt < 32; ++kt) {
    __syncthreads();  // previous PV done before we overwrite Kt/Vs
    const size_t krow0 = (size_t)b * SEQ + (size_t)kt * 64;
    {
      const int i = tid >> 2, hd0 = (tid & 3) << 4;
      const float* ksrc = qkv + (krow0 + i) * QKV_COLS + DIM + h * HEAD_DIM + hd0;
      const float* vsrc = qkv + (krow0 + i) * QKV_COLS + 2 * DIM + h * HEAD_DIM + hd0;
#pragma unroll
      for (int z = 0; z < 16; z += 4) {
        const float4 v = *(const float4*)(ksrc + z);
        Kt[hd0 + z + 0][i] = v.x;
        Kt[hd0 + z + 1][i] = v.y;
        Kt[hd0 + z + 2][i] = v.z;
        Kt[hd0 + z + 3][i] = v.w;
      }
#pragma unroll
      for (int z = 0; z < 16; z += 4) {
        *(float4*)&Vs[i][hd0 + z] = *(const float4*)(vsrc + z);
      }
    }
    if (tid < 64) kn_s[tid] = kn[(krow0 + tid) * NHEAD + h];
    __syncthreads();

    // ---- S = QK^T then hyperbolic-distance transform ----
    float dot[4][4];
#pragma unroll
    for (int i = 0; i < 4; ++i)
#pragma unroll
      for (int j = 0; j < 4; ++j) dot[i][j] = 0.f;
#pragma unroll 8
    for (int kk = 0; kk < 64; ++kk) {
      const float4 qa = *(const float4*)&Qt[kk][ty << 2];
      const float4 kb = *(const float4*)&Kt[kk][tx << 2];
      const float qv[4] = {qa.x, qa.y, qa.z, qa.w};
      const float kv[4] = {kb.x, kb.y, kb.z, kb.w};
#pragma unroll
      for (int i = 0; i < 4; ++i)
#pragma unroll
        for (int j = 0; j < 4; ++j) dot[i][j] = fmaf(qv[i], kv[j], dot[i][j]);
    }
#pragma unroll
    for (int i = 0; i < 4; ++i) {
      const float qnv = qn_s[(ty << 2) + i];
      const float qc = 1.0f - fminf(qnv, 0.99f);
#pragma unroll
      for (int j = 0; j < 4; ++j) {
        const float knv = kn_s[(tx << 2) + j];
        const float kc = 1.0f - fminf(knv, 0.99f);
        const float dsq = fmaxf(qnv + knv - 2.0f * dot[i][j], 0.0f);
        const float denom = qc * kc + 1e-8f;
        const float inner = fmaxf(1.0f + 2.0f * dsq / denom, 1.0f + 1e-7f);
        const float dist = logf(inner + sqrtf(inner * inner - 1.0f));
        Ss[(ty << 2) + i][(tx << 2) + j] = -dist * SCALE_F;
      }
    }
    __syncthreads();

    // ---- online softmax: 4 lanes per query row ----
    {
      const int r = tid >> 2, qq = tid & 3;
      float mloc = -INFINITY;
#pragma unroll
      for (int j = 0; j < 16; ++j) mloc = fmaxf(mloc, Ss[r][(qq << 4) + j]);
      mloc = fmaxf(mloc, __shfl_xor(mloc, 1, 64));
      mloc = fmaxf(mloc, __shfl_xor(mloc, 2, 64));
      const float mold = m_s[r];
      const float mnew = fmaxf(mold, mloc);
      const float alpha = expf(mold - mnew);  // first tile: exp(-inf)=0
      float sum = 0.0f;
#pragma unroll
      for (int j = 0; j < 16; ++j) {
        const float pj = expf(Ss[r][(qq << 4) + j] - mnew);
        Ss[r][(qq << 4) + j] = pj;
        sum += pj;
      }
      sum += __shfl_xor(sum, 1, 64);
      sum += __shfl_xor(sum, 2, 64);
      if (qq == 0) {
        m_s[r] = mnew;
        l_s[r] = l_s[r] * alpha + sum;
        al_s[r] = alpha;
      }
    }
    __syncthreads();

    // ---- O = O*alpha + P·V ----
#pragma unroll
    for (int i = 0; i < 4; ++i) {
      const float a = al_s[(ty << 2) + i];
#pragma unroll
      for (int j = 0; j < 4; ++j) acc[i][j] *= a;
    }
#pragma unroll 8
    for (int kk = 0; kk < 64; ++kk) {
      const float4 vv = *(const float4*)&Vs[kk][tx << 2];
      const float vr[4] = {vv.x, vv.y, vv.z, vv.w};
      float p[4];
#pragma unroll
      for (int i = 0; i < 4; ++i) p[i] = Ss[(ty << 2) + i][kk];
#pragma unroll
      for (int i = 0; i < 4; ++i)
#pragma unroll
        for (int j = 0; j < 4; ++j) acc[i][j] = fmaf(p[i], vr[j], acc[i][j]);
    }
  }
  __syncthreads();

#pragma unroll
  for (int i = 0; i < 4; ++i) {
    const int r = (ty << 2) + i;
    const float rl = 1.0f / l_s[r];
    float4 o;
    o.x = acc[i][0] * rl; o.y = acc[i][1] * rl;
    o.z = acc[i][2] * rl; o.w = acc[i][3] * rl;
    *(float4*)(attn_out + (qrow0 + r) * DIM + h * HEAD_DIM + (tx << 2)) = o;
  }
}

extern "C" void kernel_launch(void* const* d_in, const int* in_sizes, int n_in,
                              void* d_out, int out_size, void* d_ws, size_t ws_size,
                              hipStream_t stream) {
  const float* x      = (const float*)d_in[0];
  const float* w_qkv  = (const float*)d_in[1];
  const float* w_proj = (const float*)d_in[2];
  const float* b_proj = (const float*)d_in[3];
  const float* curv   = (const float*)d_in[4];
  float* outp = (float*)d_out;

  float* ws = (float*)d_ws;
  float* v_tan    = ws;                       // 4096*768  = 3,145,728 f
  float* qkv      = v_tan + 3145728;          // 4096*2304 = 9,437,184 f
  float* qn       = qkv + 9437184;            // 4096*12   = 49,152 f
  float* kn       = qn + 49152;               // 49,152 f
  float* attn_out = kn + 49152;               // 3,145,728 f
  float* v_out    = v_tan;                    // reuse (v_tan dead after GEMM1)

  log0_kernel<<<dim3(ROWS / 4), dim3(256), 0, stream>>>(x, curv, v_tan);
  sgemm_nt<<<dim3(QKV_COLS / 128, ROWS / 128), dim3(256), 0, stream>>>(
      v_tan, w_qkv, qkv, ROWS, QKV_COLS, DIM, nullptr);
  exp0_qk_kernel<<<dim3(ROWS * NHEAD * 2 / 4), dim3(256), 0, stream>>>(qkv, curv, qn, kn);
  flash_kernel<<<dim3(SEQ / 64, NHEAD, 2), dim3(256), 0, stream>>>(qkv, qn, kn, attn_out);
  sgemm_nt<<<dim3(DIM / 128, ROWS / 128), dim3(256), 0, stream>>>(
      attn_out, w_proj, v_out, ROWS, DIM, DIM, b_proj);
  exp0_out_kernel<<<dim3(ROWS / 4), dim3(256), 0, stream>>>(v_out, curv, outp);
}

// Round 2
// 570.275 us; speedup vs baseline: 1.6741x; 1.6741x over previous
//
#include <hip/hip_runtime.h>
#include <cmath>

#define ROWS 4096      // B*N
#define DIM 768        // D
#define QKV_COLS 2304  // 3*D
#define NHEAD 12
#define HEAD_DIM 64
#define SEQ 2048
#define PADK 72        // LDS row stride (bf16 elems) for 64-wide tiles: 144B rows -> uniform banks

static constexpr float SCALE_F = 0.125f;   // HD^-0.5
static constexpr float EPS_F   = 1e-8f;

typedef __bf16 bfrag __attribute__((ext_vector_type(8)));   // 8 bf16 = 4 VGPR (MFMA A/B frag)
typedef float  f32x4 __attribute__((ext_vector_type(4)));   // MFMA C/D frag

__device__ __forceinline__ float wave_sum64(float v) {
#pragma unroll
  for (int off = 1; off < 64; off <<= 1) v += __shfl_xor(v, off, 64);
  return v;
}

__device__ __forceinline__ unsigned short f2bf(float f) {
  unsigned u = __float_as_uint(f);
  u += 0x7fffu + ((u >> 16) & 1u);
  return (unsigned short)(u >> 16);
}

// ---------------- log0: v = artanh(min(sc*n,1-1e-7)) * x / (sc*n) ----------------
__global__ __launch_bounds__(256) void log0_kernel(const float* __restrict__ x,
                                                   const float* __restrict__ cptr,
                                                   float* __restrict__ vout) {
  const int lane = threadIdx.x & 63;
  const int row  = (blockIdx.x << 2) + (threadIdx.x >> 6);
  const float* xr = x + (size_t)row * DIM;
  float* vr = vout + (size_t)row * DIM;
  float vals[12];
  float ss = 0.f;
#pragma unroll
  for (int i = 0; i < 12; ++i) {
    float t = xr[lane + (i << 6)];
    vals[i] = t;
    ss += t * t;
  }
  ss = wave_sum64(ss);
  const float sc  = sqrtf(cptr[0]);
  const float n   = fmaxf(sqrtf(ss), EPS_F);
  const float scn = sc * n;
  const float t   = fminf(scn, 1.0f - 1e-7f);
  const float f   = atanhf(t) / scn;
#pragma unroll
  for (int i = 0; i < 12; ++i) vr[lane + (i << 6)] = vals[i] * f;
}

// ---------------- final exp0: out = tanh(sc*n) * v / (sc*n) ----------------
__global__ __launch_bounds__(256) void exp0_out_kernel(const float* __restrict__ vin,
                                                       const float* __restrict__ cptr,
                                                       float* __restrict__ outp) {
  const int lane = threadIdx.x & 63;
  const int row  = (blockIdx.x << 2) + (threadIdx.x >> 6);
  const float* vr = vin + (size_t)row * DIM;
  float* orow = outp + (size_t)row * DIM;
  float vals[12];
  float ss = 0.f;
#pragma unroll
  for (int i = 0; i < 12; ++i) {
    float t = vr[lane + (i << 6)];
    vals[i] = t;
    ss += t * t;
  }
  ss = wave_sum64(ss);
  const float sc  = sqrtf(cptr[0]);
  const float n   = fmaxf(sqrtf(ss), EPS_F);
  const float scn = sc * n;
  const float f   = tanhf(scn) / scn;
#pragma unroll
  for (int i = 0; i < 12; ++i) orow[lane + (i << 6)] = vals[i] * f;
}

// ---------------- SGEMM NT: C[M,Nc] = A[M,K] * B[Nc,K]^T (+bias) ----------------
__global__ __launch_bounds__(256) void sgemm_nt(const float* __restrict__ A,
                                                const float* __restrict__ Bm,
                                                float* __restrict__ C,
                                                int M, int Ncols, int K,
                                                const float* __restrict__ bias) {
  __shared__ float As[8][132];
  __shared__ float Bs[8][132];
  const int tid  = threadIdx.x;
  const int brow = blockIdx.y << 7;
  const int bcol = blockIdx.x << 7;
  const int tx = tid & 15, ty = tid >> 4;
  const int ldr = tid >> 1;
  const int ldk = (tid & 1) << 2;
  const float* Ap = A + (size_t)(brow + ldr) * K + ldk;
  const float* Bp = Bm + (size_t)(bcol + ldr) * K + ldk;
  float acc[8][8];
#pragma unroll
  for (int i = 0; i < 8; ++i)
#pragma unroll
    for (int j = 0; j < 8; ++j) acc[i][j] = 0.f;

  for (int k0 = 0; k0 < K; k0 += 8) {
    const float4 av = *(const float4*)(Ap + k0);
    const float4 bv = *(const float4*)(Bp + k0);
    __syncthreads();
    As[ldk + 0][ldr] = av.x; As[ldk + 1][ldr] = av.y;
    As[ldk + 2][ldr] = av.z; As[ldk + 3][ldr] = av.w;
    Bs[ldk + 0][ldr] = bv.x; Bs[ldk + 1][ldr] = bv.y;
    Bs[ldk + 2][ldr] = bv.z; Bs[ldk + 3][ldr] = bv.w;
    __syncthreads();
#pragma unroll
    for (int kk = 0; kk < 8; ++kk) {
      const float4 a0 = *(const float4*)&As[kk][ty << 2];
      const float4 a1 = *(const float4*)&As[kk][64 + (ty << 2)];
      const float4 b0 = *(const float4*)&Bs[kk][tx << 2];
      const float4 b1 = *(const float4*)&Bs[kk][64 + (tx << 2)];
      const float a[8] = {a0.x, a0.y, a0.z, a0.w, a1.x, a1.y, a1.z, a1.w};
      const float bq[8] = {b0.x, b0.y, b0.z, b0.w, b1.x, b1.y, b1.z, b1.w};
#pragma unroll
      for (int i = 0; i < 8; ++i)
#pragma unroll
        for (int j = 0; j < 8; ++j) acc[i][j] = fmaf(a[i], bq[j], acc[i][j]);
    }
  }

  float bvals[8];
#pragma unroll
  for (int j = 0; j < 8; ++j) {
    const int c = (j < 4) ? (tx << 2) + j : 64 + (tx << 2) + (j - 4);
    bvals[j] = bias ? bias[bcol + c] : 0.0f;
  }
#pragma unroll
  for (int i = 0; i < 8; ++i) {
    const int r = brow + ((i < 4) ? (ty << 2) + i : 64 + (ty << 2) + (i - 4));
    float* Cp = C + (size_t)r * Ncols + bcol;
    float4 o0, o1;
    o0.x = acc[i][0] + bvals[0]; o0.y = acc[i][1] + bvals[1];
    o0.z = acc[i][2] + bvals[2]; o0.w = acc[i][3] + bvals[3];
    o1.x = acc[i][4] + bvals[4]; o1.y = acc[i][5] + bvals[5];
    o1.z = acc[i][6] + bvals[6]; o1.w = acc[i][7] + bvals[7];
    *(float4*)(Cp + (tx << 2)) = o0;
    *(float4*)(Cp + 64 + (tx << 2)) = o1;
  }
}

// ------------- prep: exp0 on q,k head-vectors -> bf16 head-major + fp32 norms -------------
__global__ __launch_bounds__(256) void exp0_qk_prep(const float* __restrict__ qkv,
                                                    const float* __restrict__ cptr,
                                                    unsigned short* __restrict__ qh,
                                                    unsigned short* __restrict__ kh,
                                                    float* __restrict__ qnorm,
                                                    float* __restrict__ knorm) {
  const int lane = threadIdx.x & 63;
  const int vec  = (blockIdx.x << 2) + (threadIdx.x >> 6);  // 0..98303
  const int which = vec & 1;
  const int rest  = vec >> 1;
  const int h   = rest % NHEAD;
  const int row = rest / NHEAD;   // 0..4095
  const int b = row >> 11, n = row & 2047;
  const int bh = b * NHEAD + h;
  const float t = qkv[(size_t)row * QKV_COLS + which * DIM + h * HEAD_DIM + lane];
  const float ss = wave_sum64(t * t);
  const float sc  = sqrtf(cptr[0]);
  const float nn  = fmaxf(sqrtf(ss), EPS_F);
  const float scn = sc * nn;
  const float f   = tanhf(scn) / scn;
  const float m   = t * f;
  unsigned short* dst = (which ? kh : qh) + ((size_t)bh * SEQ + n) * HEAD_DIM + lane;
  *dst = f2bf(m);
  if (lane == 0) (which ? knorm : qnorm)[(size_t)bh * SEQ + n] = ss * f * f;
}

// ------------- prep: V head slices -> bf16 transposed [bh][d][seq] -------------
__global__ __launch_bounds__(256) void v_transpose_prep(const float* __restrict__ qkv,
                                                        unsigned short* __restrict__ vth) {
  const int kt = blockIdx.x, h = blockIdx.y, b = blockIdx.z;
  const int bh = b * NHEAD + h;
  __shared__ unsigned short T[64 * PADK];
  const int tid = threadIdx.x;
  const int r  = tid >> 2;         // key row in tile
  const int c0 = (tid & 3) << 4;   // d offset
  const float* src = qkv + ((size_t)(b * SEQ + kt * 64 + r)) * QKV_COLS + 2 * DIM + h * HEAD_DIM + c0;
#pragma unroll
  for (int z = 0; z < 16; z += 4) {
    const float4 v = *(const float4*)(src + z);
    T[(c0 + z + 0) * PADK + r] = f2bf(v.x);
    T[(c0 + z + 1) * PADK + r] = f2bf(v.y);
    T[(c0 + z + 2) * PADK + r] = f2bf(v.z);
    T[(c0 + z + 3) * PADK + r] = f2bf(v.w);
  }
  __syncthreads();
  const int d  = tid >> 2;
  const int k0 = (tid & 3) << 4;
  unsigned short* dst = vth + ((size_t)bh * HEAD_DIM + d) * SEQ + (size_t)kt * 64 + k0;
  *(uint4*)dst       = *(const uint4*)&T[d * PADK + k0];
  *(uint4*)(dst + 8) = *(const uint4*)&T[d * PADK + k0 + 8];
}

// ------------- MFMA flash attention with hyperbolic-distance scores -------------
// block = (64-q tile, h, b); 4 waves, one 16-query strip each; 64-key tiles.
__global__ __launch_bounds__(256) void flash_mfma(const unsigned short* __restrict__ qh,
                                                  const unsigned short* __restrict__ kh,
                                                  const unsigned short* __restrict__ vth,
                                                  const float* __restrict__ qnorm,
                                                  const float* __restrict__ knorm,
                                                  float* __restrict__ attn_out) {
  const int qt = blockIdx.x, h = blockIdx.y, b = blockIdx.z;
  const int bh = b * NHEAD + h;
  const int tid = threadIdx.x;
  const int w = tid >> 6, lane = tid & 63;
  const int lq = lane & 15, quad = lane >> 4;

  __shared__ unsigned short Ks[64 * PADK];
  __shared__ unsigned short Vt[64 * PADK];
  __shared__ unsigned short Ps[64 * PADK];
  __shared__ float kn_s[64];

  const unsigned short* qbase  = qh  + ((size_t)bh * SEQ + (size_t)qt * 64) * HEAD_DIM;
  const unsigned short* kbase  = kh  + (size_t)bh * SEQ * HEAD_DIM;
  const unsigned short* vtbase = vth + (size_t)bh * HEAD_DIM * SEQ;
  const float* qnb = qnorm + (size_t)bh * SEQ + (size_t)qt * 64;
  const float* knb = knorm + (size_t)bh * SEQ;

  // Q fragments (A operand): frag[l][j] = Q[w*16 + (l&15)][khf*32 + quad*8 + j]
  bfrag aq[2];
#pragma unroll
  for (int khf = 0; khf < 2; ++khf)
    aq[khf] = *(const bfrag*)(qbase + (size_t)(w * 16 + lq) * HEAD_DIM + khf * 32 + quad * 8);

  float qn4[4], qc4[4];
#pragma unroll
  for (int i = 0; i < 4; ++i) {
    qn4[i] = qnb[w * 16 + quad * 4 + i];
    qc4[i] = 1.0f - fminf(qn4[i], 0.99f);
  }

  f32x4 oacc[4];
#pragma unroll
  for (int d = 0; d < 4; ++d) oacc[d] = (f32x4){0.f, 0.f, 0.f, 0.f};
  float m4[4] = {-INFINITY, -INFINITY, -INFINITY, -INFINITY};
  float l4[4] = {0.f, 0.f, 0.f, 0.f};

  for (int kt = 0; kt < SEQ / 64; ++kt) {
    const int key0 = kt * 64;
    __syncthreads();  // previous iter's LDS reads complete
    {
      const int r  = tid >> 2;
      const int c0 = (tid & 3) << 4;
      const uint4 k0v = *(const uint4*)(kbase + (size_t)(key0 + r) * HEAD_DIM + c0);
      const uint4 k1v = *(const uint4*)(kbase + (size_t)(key0 + r) * HEAD_DIM + c0 + 8);
      const uint4 v0v = *(const uint4*)(vtbase + (size_t)r * SEQ + key0 + c0);
      const uint4 v1v = *(const uint4*)(vtbase + (size_t)r * SEQ + key0 + c0 + 8);
      *(uint4*)&Ks[r * PADK + c0]     = k0v;
      *(uint4*)&Ks[r * PADK + c0 + 8] = k1v;
      *(uint4*)&Vt[r * PADK + c0]     = v0v;
      *(uint4*)&Vt[r * PADK + c0 + 8] = v1v;
      if (tid < 64) kn_s[tid] = knb[key0 + tid];
    }
    __syncthreads();

    // ---- S strip [16q x 64k] = Q·K^T via MFMA ----
    f32x4 s[4];
#pragma unroll
    for (int st = 0; st < 4; ++st) s[st] = (f32x4){0.f, 0.f, 0.f, 0.f};
#pragma unroll
    for (int khf = 0; khf < 2; ++khf)
#pragma unroll
      for (int st = 0; st < 4; ++st) {
        const bfrag bk = *(const bfrag*)&Ks[(st * 16 + lq) * PADK + khf * 32 + quad * 8];
        s[st] = __builtin_amdgcn_mfma_f32_16x16x32_bf16(aq[khf], bk, s[st], 0, 0, 0);
      }

    // ---- hyperbolic-distance transform (C layout: row=quad*4+i, col=st*16+lq) ----
    float knv[4], kcv[4];
#pragma unroll
    for (int st = 0; st < 4; ++st) {
      knv[st] = kn_s[st * 16 + lq];
      kcv[st] = 1.0f - fminf(knv[st], 0.99f);
    }
    float p[4][4];
#pragma unroll
    for (int st = 0; st < 4; ++st)
#pragma unroll
      for (int i = 0; i < 4; ++i) {
        const float dsq = fmaxf(qn4[i] + knv[st] - 2.0f * s[st][i], 0.0f);
        const float rden = __builtin_amdgcn_rcpf(qc4[i] * kcv[st] + 1e-8f);
        const float inner = fmaxf(fmaf(2.0f * dsq, rden, 1.0f), 1.0f + 1e-7f);
        const float root = __builtin_amdgcn_sqrtf(fmaf(inner, inner, -1.0f));
        p[st][i] = -SCALE_F * __logf(inner + root);
      }

    // ---- online softmax (row state in regs; reduce over 16-lane group) ----
    float alpha4[4];
#pragma unroll
    for (int i = 0; i < 4; ++i) {
      float mloc = fmaxf(fmaxf(p[0][i], p[1][i]), fmaxf(p[2][i], p[3][i]));
      mloc = fmaxf(mloc, __shfl_xor(mloc, 1, 64));
      mloc = fmaxf(mloc, __shfl_xor(mloc, 2, 64));
      mloc = fmaxf(mloc, __shfl_xor(mloc, 4, 64));
      mloc = fmaxf(mloc, __shfl_xor(mloc, 8, 64));
      const float mnew = fmaxf(m4[i], mloc);
      alpha4[i] = __expf(m4[i] - mnew);
      m4[i] = mnew;
      float rs = 0.f;
#pragma unroll
      for (int st = 0; st < 4; ++st) {
        p[st][i] = __expf(p[st][i] - mnew);
        rs += p[st][i];
      }
      rs += __shfl_xor(rs, 1, 64);
      rs += __shfl_xor(rs, 2, 64);
      rs += __shfl_xor(rs, 4, 64);
      rs += __shfl_xor(rs, 8, 64);
      l4[i] = l4[i] * alpha4[i] + rs;
    }

    // ---- P strip -> LDS bf16 (intra-wave only: own 16-row strip, no barrier) ----
#pragma unroll
    for (int st = 0; st < 4; ++st)
#pragma unroll
      for (int i = 0; i < 4; ++i)
        Ps[(w * 16 + quad * 4 + i) * PADK + st * 16 + lq] = f2bf(p[st][i]);

    // ---- O = O*alpha + P·V ----
#pragma unroll
    for (int d = 0; d < 4; ++d)
#pragma unroll
      for (int i = 0; i < 4; ++i) oacc[d][i] *= alpha4[i];
#pragma unroll
    for (int khf = 0; khf < 2; ++khf) {
      const bfrag ap = *(const bfrag*)&Ps[(w * 16 + lq) * PADK + khf * 32 + quad * 8];
#pragma unroll
      for (int d = 0; d < 4; ++d) {
        const bfrag bv = *(const bfrag*)&Vt[(d * 16 + lq) * PADK + khf * 32 + quad * 8];
        oacc[d] = __builtin_amdgcn_mfma_f32_16x16x32_bf16(ap, bv, oacc[d], 0, 0, 0);
      }
    }
  }

  float rl4[4];
#pragma unroll
  for (int i = 0; i < 4; ++i) rl4[i] = 1.0f / l4[i];
  float* ob = attn_out + ((size_t)b * SEQ + (size_t)qt * 64 + w * 16) * DIM + h * HEAD_DIM;
#pragma unroll
  for (int d = 0; d < 4; ++d)
#pragma unroll
    for (int i = 0; i < 4; ++i)
      ob[(size_t)(quad * 4 + i) * DIM + d * 16 + lq] = oacc[d][i] * rl4[i];
}

extern "C" void kernel_launch(void* const* d_in, const int* in_sizes, int n_in,
                              void* d_out, int out_size, void* d_ws, size_t ws_size,
                              hipStream_t stream) {
  const float* x      = (const float*)d_in[0];
  const float* w_qkv  = (const float*)d_in[1];
  const float* w_proj = (const float*)d_in[2];
  const float* b_proj = (const float*)d_in[3];
  const float* curv   = (const float*)d_in[4];
  float* outp = (float*)d_out;

  float* ws = (float*)d_ws;
  // region0 (3,145,728 f): v_tan during GEMM1; then qh+kh (bf16); then v_out
  float* v_tan = ws;
  unsigned short* qh = (unsigned short*)ws;            // 3,145,728 bf16
  unsigned short* kh = qh + 3145728;                   // 3,145,728 bf16
  float* v_out = ws;                                   // after flash, qh/kh dead
  float* qkv      = ws + 3145728;                      // 9,437,184 f
  float* qnorm    = qkv + 9437184;                     // 49,152 f
  float* knorm    = qnorm + 49152;                     // 49,152 f
  float* attn_out = knorm + 49152;                     // 3,145,728 f
  unsigned short* vth = (unsigned short*)(attn_out + 3145728);  // 3,145,728 bf16

  log0_kernel<<<dim3(ROWS / 4), dim3(256), 0, stream>>>(x, curv, v_tan);
  sgemm_nt<<<dim3(QKV_COLS / 128, ROWS / 128), dim3(256), 0, stream>>>(
      v_tan, w_qkv, qkv, ROWS, QKV_COLS, DIM, nullptr);
  exp0_qk_prep<<<dim3(ROWS * NHEAD * 2 / 4), dim3(256), 0, stream>>>(qkv, curv, qh, kh,
                                                                     qnorm, knorm);
  v_transpose_prep<<<dim3(SEQ / 64, NHEAD, 2), dim3(256), 0, stream>>>(qkv, vth);
  flash_mfma<<<dim3(SEQ / 64, NHEAD, 2), dim3(256), 0, stream>>>(qh, kh, vth, qnorm,
                                                                 knorm, attn_out);
  sgemm_nt<<<dim3(DIM / 128, ROWS / 128), dim3(256), 0, stream>>>(
      attn_out, w_proj, v_out, ROWS, DIM, DIM, b_proj);
  exp0_out_kernel<<<dim3(ROWS / 4), dim3(256), 0, stream>>>(v_out, curv, outp);
}

// Round 3
// 309.216 us; speedup vs baseline: 3.0874x; 1.8443x over previous
//
#include <hip/hip_runtime.h>
#include <cmath>

#define ROWS 4096      // B*N
#define DIM 768        // D
#define QKV_COLS 2304  // 3*D
#define NHEAD 12
#define HEAD_DIM 64
#define SEQ 2048
#define PADK 72        // LDS row stride (bf16 elems) for 64-wide tiles

static constexpr float SCALE_F = 0.125f;   // HD^-0.5
static constexpr float EPS_F   = 1e-8f;

typedef __bf16 bfrag __attribute__((ext_vector_type(8)));   // 8 bf16 = 4 VGPR (MFMA A/B frag)
typedef float  f32x4 __attribute__((ext_vector_type(4)));   // MFMA C/D frag

__device__ __forceinline__ float wave_sum64(float v) {
#pragma unroll
  for (int off = 1; off < 64; off <<= 1) v += __shfl_xor(v, off, 64);
  return v;
}

__device__ __forceinline__ unsigned short f2bf(float f) {
  unsigned u = __float_as_uint(f);
  u += 0x7fffu + ((u >> 16) & 1u);
  return (unsigned short)(u >> 16);
}

__device__ __forceinline__ void gl_lds16(const void* g, void* l) {
  __builtin_amdgcn_global_load_lds((const __attribute__((address_space(1))) void*)g,
                                   (__attribute__((address_space(3))) void*)l, 16, 0, 0);
}

// ---------------- f32 -> bf16 cast (weights) ----------------
__global__ __launch_bounds__(256) void conv_bf16(const float* __restrict__ src,
                                                 unsigned short* __restrict__ dst, int n) {
  const int i = (blockIdx.x * 256 + threadIdx.x) * 4;
  if (i < n) {
    const float4 v = *(const float4*)(src + i);
    ushort4 o;
    o.x = f2bf(v.x); o.y = f2bf(v.y); o.z = f2bf(v.z); o.w = f2bf(v.w);
    *(ushort4*)(dst + i) = o;
  }
}

// ---------------- log0 -> bf16 tangent vectors ----------------
__global__ __launch_bounds__(256) void log0_kernel(const float* __restrict__ x,
                                                   const float* __restrict__ cptr,
                                                   unsigned short* __restrict__ vout) {
  const int lane = threadIdx.x & 63;
  const int row  = (blockIdx.x << 2) + (threadIdx.x >> 6);
  const float* xr = x + (size_t)row * DIM;
  unsigned short* vr = vout + (size_t)row * DIM;
  float vals[12];
  float ss = 0.f;
#pragma unroll
  for (int i = 0; i < 12; ++i) {
    float t = xr[lane + (i << 6)];
    vals[i] = t;
    ss += t * t;
  }
  ss = wave_sum64(ss);
  const float sc  = sqrtf(cptr[0]);
  const float n   = fmaxf(sqrtf(ss), EPS_F);
  const float scn = sc * n;
  const float t   = fminf(scn, 1.0f - 1e-7f);
  const float f   = atanhf(t) / scn;
#pragma unroll
  for (int i = 0; i < 12; ++i) vr[lane + (i << 6)] = f2bf(vals[i] * f);
}

// ---------------- final exp0: out = tanh(sc*n) * v / (sc*n) ----------------
__global__ __launch_bounds__(256) void exp0_out_kernel(const float* __restrict__ vin,
                                                       const float* __restrict__ cptr,
                                                       float* __restrict__ outp) {
  const int lane = threadIdx.x & 63;
  const int row  = (blockIdx.x << 2) + (threadIdx.x >> 6);
  const float* vr = vin + (size_t)row * DIM;
  float* orow = outp + (size_t)row * DIM;
  float vals[12];
  float ss = 0.f;
#pragma unroll
  for (int i = 0; i < 12; ++i) {
    float t = vr[lane + (i << 6)];
    vals[i] = t;
    ss += t * t;
  }
  ss = wave_sum64(ss);
  const float sc  = sqrtf(cptr[0]);
  const float n   = fmaxf(sqrtf(ss), EPS_F);
  const float scn = sc * n;
  const float f   = tanhf(scn) / scn;
#pragma unroll
  for (int i = 0; i < 12; ++i) orow[lane + (i << 6)] = vals[i] * f;
}

// ---------------- MFMA GEMM NT: C[M,Nc] = A[M,K]·B[Nc,K]^T (+bias), bf16 in fp32 out ----
// m97 structure: 128x128 tile, BK=32, 4 waves (2x2 of 64x64), global_load_lds width=16.
__global__ __launch_bounds__(256) void gemm_nt_mfma(const unsigned short* __restrict__ A,
                                                    const unsigned short* __restrict__ B,
                                                    float* __restrict__ C,
                                                    int M, int Ncols, int K,
                                                    const float* __restrict__ bias) {
  __shared__ unsigned short As[128 * 32];  // [row][k] rows of 64B, contiguous (gl_lds order)
  __shared__ unsigned short Bs[128 * 32];
  const int tid = threadIdx.x;
  const int w = tid >> 6, lane = tid & 63;
  const int lq = lane & 15, quad = lane >> 4;
  const int wr = w >> 1, wc = w & 1;
  const int row0 = blockIdx.y << 7;
  const int col0 = blockIdx.x << 7;

  const int srow  = lane >> 2;        // 0..15 within 16-row chunk
  const int skoff = (lane & 3) << 3;  // k elem offset 0/8/16/24

  f32x4 acc[4][4];
#pragma unroll
  for (int i = 0; i < 4; ++i)
#pragma unroll
    for (int j = 0; j < 4; ++j) acc[i][j] = (f32x4){0.f, 0.f, 0.f, 0.f};

  for (int k0 = 0; k0 < K; k0 += 32) {
    __syncthreads();  // prev iter's frag reads done
#pragma unroll
    for (int q = 0; q < 2; ++q) {
      const int r = ((w << 1) + q) << 4;  // chunk base row
      gl_lds16(A + (size_t)(row0 + r + srow) * K + k0 + skoff, &As[((w << 1) + q) << 9]);
      gl_lds16(B + (size_t)(col0 + r + srow) * K + k0 + skoff, &Bs[((w << 1) + q) << 9]);
    }
    __syncthreads();  // vmcnt drain: LDS tiles ready

    bfrag af[4], bfg[4];
#pragma unroll
    for (int i = 0; i < 4; ++i)
      af[i] = *(const bfrag*)&As[((wr << 6) + (i << 4) + lq) * 32 + (quad << 3)];
#pragma unroll
    for (int j = 0; j < 4; ++j)
      bfg[j] = *(const bfrag*)&Bs[((wc << 6) + (j << 4) + lq) * 32 + (quad << 3)];
#pragma unroll
    for (int i = 0; i < 4; ++i)
#pragma unroll
      for (int j = 0; j < 4; ++j)
        acc[i][j] = __builtin_amdgcn_mfma_f32_16x16x32_bf16(af[i], bfg[j], acc[i][j], 0, 0, 0);
  }

#pragma unroll
  for (int i = 0; i < 4; ++i) {
    const int crow = row0 + (wr << 6) + (i << 4) + (quad << 2);
#pragma unroll
    for (int j = 0; j < 4; ++j) {
      const int col = col0 + (wc << 6) + (j << 4) + lq;
      const float bj = bias ? bias[col] : 0.0f;
      float* cp = C + (size_t)crow * Ncols + col;
#pragma unroll
      for (int r = 0; r < 4; ++r)
        cp[(size_t)r * Ncols] = acc[i][j][r] + bj;
    }
  }
}

// ------------- prep: exp0 on q,k head-vectors -> bf16 head-major + fp32 norms -------------
__global__ __launch_bounds__(256) void exp0_qk_prep(const float* __restrict__ qkv,
                                                    const float* __restrict__ cptr,
                                                    unsigned short* __restrict__ qh,
                                                    unsigned short* __restrict__ kh,
                                                    float* __restrict__ qnorm,
                                                    float* __restrict__ knorm) {
  const int lane = threadIdx.x & 63;
  const int vec  = (blockIdx.x << 2) + (threadIdx.x >> 6);
  const int which = vec & 1;
  const int rest  = vec >> 1;
  const int h   = rest % NHEAD;
  const int row = rest / NHEAD;
  const int b = row >> 11, n = row & 2047;
  const int bh = b * NHEAD + h;
  const float t = qkv[(size_t)row * QKV_COLS + which * DIM + h * HEAD_DIM + lane];
  const float ss = wave_sum64(t * t);
  const float sc  = sqrtf(cptr[0]);
  const float nn  = fmaxf(sqrtf(ss), EPS_F);
  const float scn = sc * nn;
  const float f   = tanhf(scn) / scn;
  const float m   = t * f;
  unsigned short* dst = (which ? kh : qh) + ((size_t)bh * SEQ + n) * HEAD_DIM + lane;
  *dst = f2bf(m);
  if (lane == 0) (which ? knorm : qnorm)[(size_t)bh * SEQ + n] = ss * f * f;
}

// ------------- prep: V head slices -> bf16 transposed [bh][d][seq] -------------
__global__ __launch_bounds__(256) void v_transpose_prep(const float* __restrict__ qkv,
                                                        unsigned short* __restrict__ vth) {
  const int kt = blockIdx.x, h = blockIdx.y, b = blockIdx.z;
  const int bh = b * NHEAD + h;
  __shared__ unsigned short T[64 * PADK];
  const int tid = threadIdx.x;
  const int r  = tid >> 2;
  const int c0 = (tid & 3) << 4;
  const float* src = qkv + ((size_t)(b * SEQ + kt * 64 + r)) * QKV_COLS + 2 * DIM + h * HEAD_DIM + c0;
#pragma unroll
  for (int z = 0; z < 16; z += 4) {
    const float4 v = *(const float4*)(src + z);
    T[(c0 + z + 0) * PADK + r] = f2bf(v.x);
    T[(c0 + z + 1) * PADK + r] = f2bf(v.y);
    T[(c0 + z + 2) * PADK + r] = f2bf(v.z);
    T[(c0 + z + 3) * PADK + r] = f2bf(v.w);
  }
  __syncthreads();
  const int d  = tid >> 2;
  const int k0 = (tid & 3) << 4;
  unsigned short* dst = vth + ((size_t)bh * HEAD_DIM + d) * SEQ + (size_t)kt * 64 + k0;
  *(uint4*)dst       = *(const uint4*)&T[d * PADK + k0];
  *(uint4*)(dst + 8) = *(const uint4*)&T[d * PADK + k0 + 8];
}

// ------------- MFMA flash attention with hyperbolic-distance scores -------------
__global__ __launch_bounds__(256) void flash_mfma(const unsigned short* __restrict__ qh,
                                                  const unsigned short* __restrict__ kh,
                                                  const unsigned short* __restrict__ vth,
                                                  const float* __restrict__ qnorm,
                                                  const float* __restrict__ knorm,
                                                  unsigned short* __restrict__ attn_out) {
  const int qt = blockIdx.x, h = blockIdx.y, b = blockIdx.z;
  const int bh = b * NHEAD + h;
  const int tid = threadIdx.x;
  const int w = tid >> 6, lane = tid & 63;
  const int lq = lane & 15, quad = lane >> 4;

  __shared__ unsigned short Ks[64 * PADK];
  __shared__ unsigned short Vt[64 * PADK];
  __shared__ unsigned short Ps[64 * PADK];
  __shared__ float kn_s[64];

  const unsigned short* qbase  = qh  + ((size_t)bh * SEQ + (size_t)qt * 64) * HEAD_DIM;
  const unsigned short* kbase  = kh  + (size_t)bh * SEQ * HEAD_DIM;
  const unsigned short* vtbase = vth + (size_t)bh * HEAD_DIM * SEQ;
  const float* qnb = qnorm + (size_t)bh * SEQ + (size_t)qt * 64;
  const float* knb = knorm + (size_t)bh * SEQ;

  bfrag aq[2];
#pragma unroll
  for (int khf = 0; khf < 2; ++khf)
    aq[khf] = *(const bfrag*)(qbase + (size_t)(w * 16 + lq) * HEAD_DIM + khf * 32 + quad * 8);

  float qn4[4], qc4[4];
#pragma unroll
  for (int i = 0; i < 4; ++i) {
    qn4[i] = qnb[w * 16 + quad * 4 + i];
    qc4[i] = 1.0f - fminf(qn4[i], 0.99f);
  }

  f32x4 oacc[4];
#pragma unroll
  for (int d = 0; d < 4; ++d) oacc[d] = (f32x4){0.f, 0.f, 0.f, 0.f};
  float m4[4] = {-INFINITY, -INFINITY, -INFINITY, -INFINITY};
  float l4[4] = {0.f, 0.f, 0.f, 0.f};

  for (int kt = 0; kt < SEQ / 64; ++kt) {
    const int key0 = kt * 64;
    __syncthreads();
    {
      const int r  = tid >> 2;
      const int c0 = (tid & 3) << 4;
      const uint4 k0v = *(const uint4*)(kbase + (size_t)(key0 + r) * HEAD_DIM + c0);
      const uint4 k1v = *(const uint4*)(kbase + (size_t)(key0 + r) * HEAD_DIM + c0 + 8);
      const uint4 v0v = *(const uint4*)(vtbase + (size_t)r * SEQ + key0 + c0);
      const uint4 v1v = *(const uint4*)(vtbase + (size_t)r * SEQ + key0 + c0 + 8);
      *(uint4*)&Ks[r * PADK + c0]     = k0v;
      *(uint4*)&Ks[r * PADK + c0 + 8] = k1v;
      *(uint4*)&Vt[r * PADK + c0]     = v0v;
      *(uint4*)&Vt[r * PADK + c0 + 8] = v1v;
      if (tid < 64) kn_s[tid] = knb[key0 + tid];
    }
    __syncthreads();

    f32x4 s[4];
#pragma unroll
    for (int st = 0; st < 4; ++st) s[st] = (f32x4){0.f, 0.f, 0.f, 0.f};
#pragma unroll
    for (int khf = 0; khf < 2; ++khf)
#pragma unroll
      for (int st = 0; st < 4; ++st) {
        const bfrag bk = *(const bfrag*)&Ks[(st * 16 + lq) * PADK + khf * 32 + quad * 8];
        s[st] = __builtin_amdgcn_mfma_f32_16x16x32_bf16(aq[khf], bk, s[st], 0, 0, 0);
      }

    float knv[4], kcv[4];
#pragma unroll
    for (int st = 0; st < 4; ++st) {
      knv[st] = kn_s[st * 16 + lq];
      kcv[st] = 1.0f - fminf(knv[st], 0.99f);
    }
    float p[4][4];
#pragma unroll
    for (int st = 0; st < 4; ++st)
#pragma unroll
      for (int i = 0; i < 4; ++i) {
        const float dsq = fmaxf(qn4[i] + knv[st] - 2.0f * s[st][i], 0.0f);
        const float rden = __builtin_amdgcn_rcpf(qc4[i] * kcv[st] + 1e-8f);
        const float inner = fmaxf(fmaf(2.0f * dsq, rden, 1.0f), 1.0f + 1e-7f);
        const float root = __builtin_amdgcn_sqrtf(fmaf(inner, inner, -1.0f));
        p[st][i] = -SCALE_F * __logf(inner + root);
      }

    float alpha4[4];
#pragma unroll
    for (int i = 0; i < 4; ++i) {
      float mloc = fmaxf(fmaxf(p[0][i], p[1][i]), fmaxf(p[2][i], p[3][i]));
      mloc = fmaxf(mloc, __shfl_xor(mloc, 1, 64));
      mloc = fmaxf(mloc, __shfl_xor(mloc, 2, 64));
      mloc = fmaxf(mloc, __shfl_xor(mloc, 4, 64));
      mloc = fmaxf(mloc, __shfl_xor(mloc, 8, 64));
      const float mnew = fmaxf(m4[i], mloc);
      alpha4[i] = __expf(m4[i] - mnew);
      m4[i] = mnew;
      float rs = 0.f;
#pragma unroll
      for (int st = 0; st < 4; ++st) {
        p[st][i] = __expf(p[st][i] - mnew);
        rs += p[st][i];
      }
      rs += __shfl_xor(rs, 1, 64);
      rs += __shfl_xor(rs, 2, 64);
      rs += __shfl_xor(rs, 4, 64);
      rs += __shfl_xor(rs, 8, 64);
      l4[i] = l4[i] * alpha4[i] + rs;
    }

#pragma unroll
    for (int st = 0; st < 4; ++st)
#pragma unroll
      for (int i = 0; i < 4; ++i)
        Ps[(w * 16 + quad * 4 + i) * PADK + st * 16 + lq] = f2bf(p[st][i]);

#pragma unroll
    for (int d = 0; d < 4; ++d)
#pragma unroll
      for (int i = 0; i < 4; ++i) oacc[d][i] *= alpha4[i];
#pragma unroll
    for (int khf = 0; khf < 2; ++khf) {
      const bfrag ap = *(const bfrag*)&Ps[(w * 16 + lq) * PADK + khf * 32 + quad * 8];
#pragma unroll
      for (int d = 0; d < 4; ++d) {
        const bfrag bv = *(const bfrag*)&Vt[(d * 16 + lq) * PADK + khf * 32 + quad * 8];
        oacc[d] = __builtin_amdgcn_mfma_f32_16x16x32_bf16(ap, bv, oacc[d], 0, 0, 0);
      }
    }
  }

  float rl4[4];
#pragma unroll
  for (int i = 0; i < 4; ++i) rl4[i] = 1.0f / l4[i];
  unsigned short* ob = attn_out + ((size_t)b * SEQ + (size_t)qt * 64 + w * 16) * DIM + h * HEAD_DIM;
#pragma unroll
  for (int d = 0; d < 4; ++d)
#pragma unroll
    for (int i = 0; i < 4; ++i)
      ob[(size_t)(quad * 4 + i) * DIM + d * 16 + lq] = f2bf(oacc[d][i] * rl4[i]);
}

extern "C" void kernel_launch(void* const* d_in, const int* in_sizes, int n_in,
                              void* d_out, int out_size, void* d_ws, size_t ws_size,
                              hipStream_t stream) {
  const float* x      = (const float*)d_in[0];
  const float* w_qkv  = (const float*)d_in[1];
  const float* w_proj = (const float*)d_in[2];
  const float* b_proj = (const float*)d_in[3];
  const float* curv   = (const float*)d_in[4];
  float* outp = (float*)d_out;

  float* ws = (float*)d_ws;
  // region A (1,572,864 f): v_tan_bf during GEMM1; attn_bf during GEMM2
  unsigned short* v_tan_bf = (unsigned short*)ws;
  unsigned short* attn_bf  = (unsigned short*)ws;
  // region B (9,437,184 f): qkv fp32; reused as v_out fp32 after flash
  float* qkv   = ws + 1572864;
  float* v_out = qkv;
  // region C: qh, kh, vth (bf16, 3,145,728 each)
  unsigned short* qh  = (unsigned short*)(qkv + 9437184);
  unsigned short* kh  = qh + 3145728;
  unsigned short* vth = kh + 3145728;
  // region D: weights bf16
  unsigned short* wqkv_bf  = vth + 3145728;
  unsigned short* wproj_bf = wqkv_bf + 1769472;
  // region E: norms
  float* qnorm = (float*)(wproj_bf + 589824);
  float* knorm = qnorm + 49152;

  conv_bf16<<<dim3((1769472 / 4 + 255) / 256), dim3(256), 0, stream>>>(w_qkv, wqkv_bf, 1769472);
  conv_bf16<<<dim3((589824 / 4 + 255) / 256), dim3(256), 0, stream>>>(w_proj, wproj_bf, 589824);
  log0_kernel<<<dim3(ROWS / 4), dim3(256), 0, stream>>>(x, curv, v_tan_bf);
  gemm_nt_mfma<<<dim3(QKV_COLS / 128, ROWS / 128), dim3(256), 0, stream>>>(
      v_tan_bf, wqkv_bf, qkv, ROWS, QKV_COLS, DIM, nullptr);
  exp0_qk_prep<<<dim3(ROWS * NHEAD * 2 / 4), dim3(256), 0, stream>>>(qkv, curv, qh, kh,
                                                                     qnorm, knorm);
  v_transpose_prep<<<dim3(SEQ / 64, NHEAD, 2), dim3(256), 0, stream>>>(qkv, vth);
  flash_mfma<<<dim3(SEQ / 64, NHEAD, 2), dim3(256), 0, stream>>>(qh, kh, vth, qnorm,
                                                                 knorm, attn_bf);
  gemm_nt_mfma<<<dim3(DIM / 128, ROWS / 128), dim3(256), 0, stream>>>(
      attn_bf, wproj_bf, v_out, ROWS, DIM, DIM, b_proj);
  exp0_out_kernel<<<dim3(ROWS / 4), dim3(256), 0, stream>>>(v_out, curv, outp);
}

// Round 4
// 241.189 us; speedup vs baseline: 3.9582x; 1.2820x over previous
//
#include <hip/hip_runtime.h>
#include <cmath>

#define ROWS 4096      // B*N
#define DIM 768        // D
#define QKV_COLS 2304  // 3*D
#define NHEAD 12
#define HEAD_DIM 64
#define SEQ 2048
#define PADK 72        // LDS row stride (bf16) for VALU-written tiles (Ps, transpose scratch)

static constexpr float SCALE_F = 0.125f;   // HD^-0.5
static constexpr float EPS_F   = 1e-8f;

typedef __bf16 bfrag __attribute__((ext_vector_type(8)));   // 8 bf16 = 4 VGPR (MFMA A/B frag)
typedef float  f32x4 __attribute__((ext_vector_type(4)));   // MFMA C/D frag

__device__ __forceinline__ float wave_sum64(float v) {
#pragma unroll
  for (int off = 1; off < 64; off <<= 1) v += __shfl_xor(v, off, 64);
  return v;
}

__device__ __forceinline__ unsigned short f2bf(float f) {
  unsigned u = __float_as_uint(f);
  u += 0x7fffu + ((u >> 16) & 1u);
  return (unsigned short)(u >> 16);
}

__device__ __forceinline__ void gl_lds16(const void* g, void* l) {
  __builtin_amdgcn_global_load_lds((const __attribute__((address_space(1))) void*)g,
                                   (__attribute__((address_space(3))) void*)l, 16, 0, 0);
}

// ---------------- f32 -> bf16 cast (weights) ----------------
__global__ __launch_bounds__(256) void conv_bf16(const float* __restrict__ src,
                                                 unsigned short* __restrict__ dst, int n) {
  const int i = (blockIdx.x * 256 + threadIdx.x) * 4;
  if (i < n) {
    const float4 v = *(const float4*)(src + i);
    ushort4 o;
    o.x = f2bf(v.x); o.y = f2bf(v.y); o.z = f2bf(v.z); o.w = f2bf(v.w);
    *(ushort4*)(dst + i) = o;
  }
}

// ---------------- log0 -> bf16 tangent vectors ----------------
__global__ __launch_bounds__(256) void log0_kernel(const float* __restrict__ x,
                                                   const float* __restrict__ cptr,
                                                   unsigned short* __restrict__ vout) {
  const int lane = threadIdx.x & 63;
  const int row  = (blockIdx.x << 2) + (threadIdx.x >> 6);
  const float* xr = x + (size_t)row * DIM;
  unsigned short* vr = vout + (size_t)row * DIM;
  float vals[12];
  float ss = 0.f;
#pragma unroll
  for (int i = 0; i < 12; ++i) {
    float t = xr[lane + (i << 6)];
    vals[i] = t;
    ss += t * t;
  }
  ss = wave_sum64(ss);
  const float sc  = sqrtf(cptr[0]);
  const float n   = fmaxf(sqrtf(ss), EPS_F);
  const float scn = sc * n;
  const float t   = fminf(scn, 1.0f - 1e-7f);
  const float f   = atanhf(t) / scn;
#pragma unroll
  for (int i = 0; i < 12; ++i) vr[lane + (i << 6)] = f2bf(vals[i] * f);
}

// ---------------- final exp0: out = tanh(sc*n) * v / (sc*n) ----------------
__global__ __launch_bounds__(256) void exp0_out_kernel(const float* __restrict__ vin,
                                                       const float* __restrict__ cptr,
                                                       float* __restrict__ outp) {
  const int lane = threadIdx.x & 63;
  const int row  = (blockIdx.x << 2) + (threadIdx.x >> 6);
  const float* vr = vin + (size_t)row * DIM;
  float* orow = outp + (size_t)row * DIM;
  float vals[12];
  float ss = 0.f;
#pragma unroll
  for (int i = 0; i < 12; ++i) {
    float t = vr[lane + (i << 6)];
    vals[i] = t;
    ss += t * t;
  }
  ss = wave_sum64(ss);
  const float sc  = sqrtf(cptr[0]);
  const float n   = fmaxf(sqrtf(ss), EPS_F);
  const float scn = sc * n;
  const float f   = tanhf(scn) / scn;
#pragma unroll
  for (int i = 0; i < 12; ++i) orow[lane + (i << 6)] = vals[i] * f;
}

// ---------------- MFMA GEMM NT (m97 structure) ----------------
__global__ __launch_bounds__(256) void gemm_nt_mfma(const unsigned short* __restrict__ A,
                                                    const unsigned short* __restrict__ B,
                                                    float* __restrict__ C,
                                                    int M, int Ncols, int K,
                                                    const float* __restrict__ bias) {
  __shared__ unsigned short As[128 * 32];
  __shared__ unsigned short Bs[128 * 32];
  const int tid = threadIdx.x;
  const int w = tid >> 6, lane = tid & 63;
  const int lq = lane & 15, quad = lane >> 4;
  const int wr = w >> 1, wc = w & 1;
  const int row0 = blockIdx.y << 7;
  const int col0 = blockIdx.x << 7;

  const int srow  = lane >> 2;
  const int skoff = (lane & 3) << 3;

  f32x4 acc[4][4];
#pragma unroll
  for (int i = 0; i < 4; ++i)
#pragma unroll
    for (int j = 0; j < 4; ++j) acc[i][j] = (f32x4){0.f, 0.f, 0.f, 0.f};

  for (int k0 = 0; k0 < K; k0 += 32) {
    __syncthreads();
#pragma unroll
    for (int q = 0; q < 2; ++q) {
      const int r = ((w << 1) + q) << 4;
      gl_lds16(A + (size_t)(row0 + r + srow) * K + k0 + skoff, &As[((w << 1) + q) << 9]);
      gl_lds16(B + (size_t)(col0 + r + srow) * K + k0 + skoff, &Bs[((w << 1) + q) << 9]);
    }
    __syncthreads();

    bfrag af[4], bfg[4];
#pragma unroll
    for (int i = 0; i < 4; ++i)
      af[i] = *(const bfrag*)&As[((wr << 6) + (i << 4) + lq) * 32 + (quad << 3)];
#pragma unroll
    for (int j = 0; j < 4; ++j)
      bfg[j] = *(const bfrag*)&Bs[((wc << 6) + (j << 4) + lq) * 32 + (quad << 3)];
#pragma unroll
    for (int i = 0; i < 4; ++i)
#pragma unroll
      for (int j = 0; j < 4; ++j)
        acc[i][j] = __builtin_amdgcn_mfma_f32_16x16x32_bf16(af[i], bfg[j], acc[i][j], 0, 0, 0);
  }

#pragma unroll
  for (int i = 0; i < 4; ++i) {
    const int crow = row0 + (wr << 6) + (i << 4) + (quad << 2);
#pragma unroll
    for (int j = 0; j < 4; ++j) {
      const int col = col0 + (wc << 6) + (j << 4) + lq;
      const float bj = bias ? bias[col] : 0.0f;
      float* cp = C + (size_t)crow * Ncols + col;
#pragma unroll
      for (int r = 0; r < 4; ++r)
        cp[(size_t)r * Ncols] = acc[i][j][r] + bj;
    }
  }
}

// ------------- prep: exp0 on q,k head-vectors -> bf16 head-major + (norm, 1/(1-clamp)) ---
__global__ __launch_bounds__(256) void exp0_qk_prep(const float* __restrict__ qkv,
                                                    const float* __restrict__ cptr,
                                                    unsigned short* __restrict__ qh,
                                                    unsigned short* __restrict__ kh,
                                                    float2* __restrict__ qn2,
                                                    float2* __restrict__ kn2) {
  const int lane = threadIdx.x & 63;
  const int vec  = (blockIdx.x << 2) + (threadIdx.x >> 6);
  const int which = vec & 1;
  const int rest  = vec >> 1;
  const int h   = rest % NHEAD;
  const int row = rest / NHEAD;
  const int b = row >> 11, n = row & 2047;
  const int bh = b * NHEAD + h;
  const float t = qkv[(size_t)row * QKV_COLS + which * DIM + h * HEAD_DIM + lane];
  const float ss = wave_sum64(t * t);
  const float sc  = sqrtf(cptr[0]);
  const float nn  = fmaxf(sqrtf(ss), EPS_F);
  const float scn = sc * nn;
  const float f   = tanhf(scn) / scn;
  const float m   = t * f;
  unsigned short* dst = (which ? kh : qh) + ((size_t)bh * SEQ + n) * HEAD_DIM + lane;
  *dst = f2bf(m);
  if (lane == 0) {
    const float nrm = ss * f * f;
    const float rc  = 1.0f / (1.0f - fminf(nrm, 0.99f));
    (which ? kn2 : qn2)[(size_t)bh * SEQ + n] = make_float2(nrm, rc);
  }
}

// ------------- prep: V head slices -> bf16 transposed [bh][d][seq] -------------
__global__ __launch_bounds__(256) void v_transpose_prep(const float* __restrict__ qkv,
                                                        unsigned short* __restrict__ vth) {
  const int kt = blockIdx.x, h = blockIdx.y, b = blockIdx.z;
  const int bh = b * NHEAD + h;
  __shared__ unsigned short T[64 * PADK];
  const int tid = threadIdx.x;
  const int r  = tid >> 2;
  const int c0 = (tid & 3) << 4;
  const float* src = qkv + ((size_t)(b * SEQ + kt * 64 + r)) * QKV_COLS + 2 * DIM + h * HEAD_DIM + c0;
#pragma unroll
  for (int z = 0; z < 16; z += 4) {
    const float4 v = *(const float4*)(src + z);
    T[(c0 + z + 0) * PADK + r] = f2bf(v.x);
    T[(c0 + z + 1) * PADK + r] = f2bf(v.y);
    T[(c0 + z + 2) * PADK + r] = f2bf(v.z);
    T[(c0 + z + 3) * PADK + r] = f2bf(v.w);
  }
  __syncthreads();
  const int d  = tid >> 2;
  const int k0 = (tid & 3) << 4;
  unsigned short* dst = vth + ((size_t)bh * HEAD_DIM + d) * SEQ + (size_t)kt * 64 + k0;
  *(uint4*)dst       = *(const uint4*)&T[d * PADK + k0];
  *(uint4*)(dst + 8) = *(const uint4*)&T[d * PADK + k0 + 8];
}

// ------------- MFMA flash attention, w-direct softmax (no max/alpha) -------------
// block = (64-q tile, h, b); 4 waves x 16-query strips; 64-key tiles.
// K/V staged with global_load_lds into XOR-swizzled 128B rows (pos = blk ^ (row&7)).
__global__ __launch_bounds__(256) void flash_mfma(const unsigned short* __restrict__ qh,
                                                  const unsigned short* __restrict__ kh,
                                                  const unsigned short* __restrict__ vth,
                                                  const float2* __restrict__ qn2,
                                                  const float2* __restrict__ kn2,
                                                  unsigned short* __restrict__ attn_out) {
  const int qt = blockIdx.x, h = blockIdx.y, b = blockIdx.z;
  const int bh = b * NHEAD + h;
  const int tid = threadIdx.x;
  const int w = tid >> 6, lane = tid & 63;
  const int lq = lane & 15, quad = lane >> 4;

  __shared__ unsigned short Ks[64 * 64];   // swizzled [key][hd]
  __shared__ unsigned short Vt[64 * 64];   // swizzled [d][key]
  __shared__ unsigned short Ps[64 * PADK]; // [q][key], stride 72
  __shared__ float2 kn_s[64];

  const unsigned short* qbase = qh + ((size_t)bh * SEQ + (size_t)qt * 64) * HEAD_DIM;
  const float2* qnb = qn2 + (size_t)bh * SEQ + (size_t)qt * 64;
  const float2* knb = kn2 + (size_t)bh * SEQ;

  // staging source addressing (swizzled): slot row = tid>>3, pos = tid&7
  const int srow = tid >> 3, spos = tid & 7;
  const int sB = spos ^ (srow & 7);
  const char* kgsrc = (const char*)(kh + (size_t)bh * SEQ * HEAD_DIM) + (size_t)srow * 128 + sB * 16;
  const char* vgsrc = (const char*)(vth + (size_t)bh * HEAD_DIM * SEQ) + (size_t)srow * 4096 + sB * 16;

  bfrag aq[2];
#pragma unroll
  for (int khf = 0; khf < 2; ++khf)
    aq[khf] = *(const bfrag*)(qbase + (size_t)(w * 16 + lq) * HEAD_DIM + khf * 32 + quad * 8);

  float qn4[4], rq2[4];
#pragma unroll
  for (int i = 0; i < 4; ++i) {
    const float2 qq = qnb[w * 16 + quad * 4 + i];
    qn4[i] = qq.x;
    rq2[i] = 2.0f * qq.y;
  }

  f32x4 oacc[4];
#pragma unroll
  for (int d = 0; d < 4; ++d) oacc[d] = (f32x4){0.f, 0.f, 0.f, 0.f};
  float l4[4] = {0.f, 0.f, 0.f, 0.f};

  const int swz = (lq & 7);  // frag-read swizzle term (row&7 == lq&7 for all our reads)

  for (int kt = 0; kt < SEQ / 64; ++kt) {
    __syncthreads();  // all waves done reading prev tiles
    gl_lds16(kgsrc,          (char*)Ks + w * 1024);
    gl_lds16(kgsrc + 4096,   (char*)Ks + 4096 + w * 1024);
    gl_lds16(vgsrc,          (char*)Vt + w * 1024);
    gl_lds16(vgsrc + 131072, (char*)Vt + 4096 + w * 1024);
    if (tid < 64) kn_s[tid] = knb[kt * 64 + tid];
    kgsrc += 8192;   // 64 keys * 128B
    vgsrc += 128;    // 64 keys * 2B per row
    __syncthreads();  // vmcnt/lgkm drain: tiles ready

    // ---- S strip [16q x 64k] = Q·K^T via MFMA ----
    f32x4 s[4];
#pragma unroll
    for (int st = 0; st < 4; ++st) s[st] = (f32x4){0.f, 0.f, 0.f, 0.f};
#pragma unroll
    for (int khf = 0; khf < 2; ++khf)
#pragma unroll
      for (int st = 0; st < 4; ++st) {
        const bfrag bk = *(const bfrag*)&Ks[(st * 16 + lq) * 64 + (((khf << 2) + quad) ^ swz) * 8];
        s[st] = __builtin_amdgcn_mfma_f32_16x16x32_bf16(aq[khf], bk, s[st], 0, 0, 0);
      }

    // ---- w = (inner + sqrt(inner^2-1))^(-1/8) ; accumulate l from truncated bf16 ----
#pragma unroll
    for (int st = 0; st < 4; ++st) {
      const float2 kk = kn_s[st * 16 + lq];
#pragma unroll
      for (int i = 0; i < 4; ++i) {
        float t = fmaf(-2.0f, s[st][i], qn4[i] + kk.x);
        t = fmaxf(t, 0.0f);
        const float inner = fmaf(t, rq2[i] * kk.y, 1.0f);
        const float root = __builtin_amdgcn_sqrtf(fmaf(inner, inner, -1.0f));
        const float wgt = __builtin_amdgcn_exp2f(-0.125f * __builtin_amdgcn_logf(inner + root));
        const unsigned u = __float_as_uint(wgt);
        Ps[(w * 16 + quad * 4 + i) * PADK + st * 16 + lq] = (unsigned short)(u >> 16);
        l4[i] += __uint_as_float(u & 0xffff0000u);
      }
    }

    // ---- O += P·V (intra-wave Ps strip: DS ops in-order, no barrier) ----
#pragma unroll
    for (int khf = 0; khf < 2; ++khf) {
      const bfrag ap = *(const bfrag*)&Ps[(w * 16 + lq) * PADK + khf * 32 + quad * 8];
#pragma unroll
      for (int d = 0; d < 4; ++d) {
        const bfrag bv = *(const bfrag*)&Vt[(d * 16 + lq) * 64 + (((khf << 2) + quad) ^ swz) * 8];
        oacc[d] = __builtin_amdgcn_mfma_f32_16x16x32_bf16(ap, bv, oacc[d], 0, 0, 0);
      }
    }
  }

  // ---- final l reduce across the 16-lane row group, then normalize ----
  float rl4[4];
#pragma unroll
  for (int i = 0; i < 4; ++i) {
    float s_ = l4[i];
    s_ += __shfl_xor(s_, 1, 64);
    s_ += __shfl_xor(s_, 2, 64);
    s_ += __shfl_xor(s_, 4, 64);
    s_ += __shfl_xor(s_, 8, 64);
    rl4[i] = __builtin_amdgcn_rcpf(s_);
  }
  unsigned short* ob = attn_out + ((size_t)b * SEQ + (size_t)qt * 64 + w * 16) * DIM + h * HEAD_DIM;
#pragma unroll
  for (int d = 0; d < 4; ++d)
#pragma unroll
    for (int i = 0; i < 4; ++i)
      ob[(size_t)(quad * 4 + i) * DIM + d * 16 + lq] = f2bf(oacc[d][i] * rl4[i]);
}

extern "C" void kernel_launch(void* const* d_in, const int* in_sizes, int n_in,
                              void* d_out, int out_size, void* d_ws, size_t ws_size,
                              hipStream_t stream) {
  const float* x      = (const float*)d_in[0];
  const float* w_qkv  = (const float*)d_in[1];
  const float* w_proj = (const float*)d_in[2];
  const float* b_proj = (const float*)d_in[3];
  const float* curv   = (const float*)d_in[4];
  float* outp = (float*)d_out;

  float* ws = (float*)d_ws;
  // region A (1,572,864 f): v_tan_bf during GEMM1; attn_bf during GEMM2
  unsigned short* v_tan_bf = (unsigned short*)ws;
  unsigned short* attn_bf  = (unsigned short*)ws;
  // region B (9,437,184 f): qkv fp32; reused as v_out fp32 after flash
  float* qkv   = ws + 1572864;
  float* v_out = qkv;
  // region C: qh, kh, vth (bf16, 3,145,728 each)
  unsigned short* qh  = (unsigned short*)(qkv + 9437184);
  unsigned short* kh  = qh + 3145728;
  unsigned short* vth = kh + 3145728;
  // region D: weights bf16
  unsigned short* wqkv_bf  = vth + 3145728;
  unsigned short* wproj_bf = wqkv_bf + 1769472;
  // region E: (norm, reciprocal) pairs
  float2* qn2 = (float2*)(wproj_bf + 589824);
  float2* kn2 = qn2 + 49152;

  conv_bf16<<<dim3((1769472 / 4 + 255) / 256), dim3(256), 0, stream>>>(w_qkv, wqkv_bf, 1769472);
  conv_bf16<<<dim3((589824 / 4 + 255) / 256), dim3(256), 0, stream>>>(w_proj, wproj_bf, 589824);
  log0_kernel<<<dim3(ROWS / 4), dim3(256), 0, stream>>>(x, curv, v_tan_bf);
  gemm_nt_mfma<<<dim3(QKV_COLS / 128, ROWS / 128), dim3(256), 0, stream>>>(
      v_tan_bf, wqkv_bf, qkv, ROWS, QKV_COLS, DIM, nullptr);
  exp0_qk_prep<<<dim3(ROWS * NHEAD * 2 / 4), dim3(256), 0, stream>>>(qkv, curv, qh, kh,
                                                                     qn2, kn2);
  v_transpose_prep<<<dim3(SEQ / 64, NHEAD, 2), dim3(256), 0, stream>>>(qkv, vth);
  flash_mfma<<<dim3(SEQ / 64, NHEAD, 2), dim3(256), 0, stream>>>(qh, kh, vth, qn2,
                                                                 kn2, attn_bf);
  gemm_nt_mfma<<<dim3(DIM / 128, ROWS / 128), dim3(256), 0, stream>>>(
      attn_bf, wproj_bf, v_out, ROWS, DIM, DIM, b_proj);
  exp0_out_kernel<<<dim3(ROWS / 4), dim3(256), 0, stream>>>(v_out, curv, outp);
}

// Round 5
// 234.455 us; speedup vs baseline: 4.0719x; 1.0287x over previous
//
#include <hip/hip_runtime.h>
#include <cmath>

#define ROWS 4096      // B*N
#define DIM 768        // D
#define QKV_COLS 2304  // 3*D
#define NHEAD 12
#define HEAD_DIM 64
#define SEQ 2048
#define PADK 72        // LDS row stride (bf16) for VALU-written tiles (Ps, transpose scratch)

static constexpr float SCALE_F = 0.125f;   // HD^-0.5
static constexpr float EPS_F   = 1e-8f;

typedef __bf16 bfrag __attribute__((ext_vector_type(8)));   // 8 bf16 = 4 VGPR (MFMA A/B frag)
typedef float  f32x4 __attribute__((ext_vector_type(4)));   // MFMA C/D frag

__device__ __forceinline__ float wave_sum64(float v) {
#pragma unroll
  for (int off = 1; off < 64; off <<= 1) v += __shfl_xor(v, off, 64);
  return v;
}

__device__ __forceinline__ unsigned short f2bf(float f) {
  unsigned u = __float_as_uint(f);
  u += 0x7fffu + ((u >> 16) & 1u);
  return (unsigned short)(u >> 16);
}

__device__ __forceinline__ void gl_lds16(const void* g, void* l) {
  __builtin_amdgcn_global_load_lds((const __attribute__((address_space(1))) void*)g,
                                   (__attribute__((address_space(3))) void*)l, 16, 0, 0);
}

// ---------------- f32 -> bf16 cast (both weight tensors, one launch) ----------------
__global__ __launch_bounds__(256) void conv_bf16_2(const float* __restrict__ a, int na,
                                                   const float* __restrict__ b, int nb,
                                                   unsigned short* __restrict__ da,
                                                   unsigned short* __restrict__ db) {
  const int i = (blockIdx.x * 256 + threadIdx.x) * 4;
  const float* s;
  unsigned short* d;
  int j;
  if (i < na) { s = a; d = da; j = i; }
  else { j = i - na; if (j >= nb) return; s = b; d = db; }
  const float4 v = *(const float4*)(s + j);
  ushort4 o;
  o.x = f2bf(v.x); o.y = f2bf(v.y); o.z = f2bf(v.z); o.w = f2bf(v.w);
  *(ushort4*)(d + j) = o;
}

// ---------------- log0 -> bf16 tangent vectors ----------------
__global__ __launch_bounds__(256) void log0_kernel(const float* __restrict__ x,
                                                   const float* __restrict__ cptr,
                                                   unsigned short* __restrict__ vout) {
  const int lane = threadIdx.x & 63;
  const int row  = (blockIdx.x << 2) + (threadIdx.x >> 6);
  const float* xr = x + (size_t)row * DIM;
  unsigned short* vr = vout + (size_t)row * DIM;
  float vals[12];
  float ss = 0.f;
#pragma unroll
  for (int i = 0; i < 12; ++i) {
    float t = xr[lane + (i << 6)];
    vals[i] = t;
    ss += t * t;
  }
  ss = wave_sum64(ss);
  const float sc  = sqrtf(cptr[0]);
  const float n   = fmaxf(sqrtf(ss), EPS_F);
  const float scn = sc * n;
  const float t   = fminf(scn, 1.0f - 1e-7f);
  const float f   = atanhf(t) / scn;
#pragma unroll
  for (int i = 0; i < 12; ++i) vr[lane + (i << 6)] = f2bf(vals[i] * f);
}

// ---------------- final exp0: out = tanh(sc*n) * v / (sc*n) ----------------
__global__ __launch_bounds__(256) void exp0_out_kernel(const float* __restrict__ vin,
                                                       const float* __restrict__ cptr,
                                                       float* __restrict__ outp) {
  const int lane = threadIdx.x & 63;
  const int row  = (blockIdx.x << 2) + (threadIdx.x >> 6);
  const float* vr = vin + (size_t)row * DIM;
  float* orow = outp + (size_t)row * DIM;
  float vals[12];
  float ss = 0.f;
#pragma unroll
  for (int i = 0; i < 12; ++i) {
    float t = vr[lane + (i << 6)];
    vals[i] = t;
    ss += t * t;
  }
  ss = wave_sum64(ss);
  const float sc  = sqrtf(cptr[0]);
  const float n   = fmaxf(sqrtf(ss), EPS_F);
  const float scn = sc * n;
  const float f   = tanhf(scn) / scn;
#pragma unroll
  for (int i = 0; i < 12; ++i) orow[lane + (i << 6)] = vals[i] * f;
}

// ---------------- MFMA GEMM NT (m97 structure) ----------------
__global__ __launch_bounds__(256) void gemm_nt_mfma(const unsigned short* __restrict__ A,
                                                    const unsigned short* __restrict__ B,
                                                    float* __restrict__ C,
                                                    int M, int Ncols, int K,
                                                    const float* __restrict__ bias) {
  __shared__ unsigned short As[128 * 32];
  __shared__ unsigned short Bs[128 * 32];
  const int tid = threadIdx.x;
  const int w = tid >> 6, lane = tid & 63;
  const int lq = lane & 15, quad = lane >> 4;
  const int wr = w >> 1, wc = w & 1;
  const int row0 = blockIdx.y << 7;
  const int col0 = blockIdx.x << 7;

  const int srow  = lane >> 2;
  const int skoff = (lane & 3) << 3;

  f32x4 acc[4][4];
#pragma unroll
  for (int i = 0; i < 4; ++i)
#pragma unroll
    for (int j = 0; j < 4; ++j) acc[i][j] = (f32x4){0.f, 0.f, 0.f, 0.f};

  for (int k0 = 0; k0 < K; k0 += 32) {
    __syncthreads();
#pragma unroll
    for (int q = 0; q < 2; ++q) {
      const int r = ((w << 1) + q) << 4;
      gl_lds16(A + (size_t)(row0 + r + srow) * K + k0 + skoff, &As[((w << 1) + q) << 9]);
      gl_lds16(B + (size_t)(col0 + r + srow) * K + k0 + skoff, &Bs[((w << 1) + q) << 9]);
    }
    __syncthreads();

    bfrag af[4], bfg[4];
#pragma unroll
    for (int i = 0; i < 4; ++i)
      af[i] = *(const bfrag*)&As[((wr << 6) + (i << 4) + lq) * 32 + (quad << 3)];
#pragma unroll
    for (int j = 0; j < 4; ++j)
      bfg[j] = *(const bfrag*)&Bs[((wc << 6) + (j << 4) + lq) * 32 + (quad << 3)];
#pragma unroll
    for (int i = 0; i < 4; ++i)
#pragma unroll
      for (int j = 0; j < 4; ++j)
        acc[i][j] = __builtin_amdgcn_mfma_f32_16x16x32_bf16(af[i], bfg[j], acc[i][j], 0, 0, 0);
  }

#pragma unroll
  for (int i = 0; i < 4; ++i) {
    const int crow = row0 + (wr << 6) + (i << 4) + (quad << 2);
#pragma unroll
    for (int j = 0; j < 4; ++j) {
      const int col = col0 + (wc << 6) + (j << 4) + lq;
      const float bj = bias ? bias[col] : 0.0f;
      float* cp = C + (size_t)crow * Ncols + col;
#pragma unroll
      for (int r = 0; r < 4; ++r)
        cp[(size_t)r * Ncols] = acc[i][j][r] + bj;
    }
  }
}

// ------------- fused prep: exp0(q,k) -> bf16 head-major + norms; V -> bf16 transposed ----
// grid (SEQ/64, NHEAD, B), 256 threads
__global__ __launch_bounds__(256) void qkv_prep(const float* __restrict__ qkv,
                                                const float* __restrict__ cptr,
                                                unsigned short* __restrict__ qh,
                                                unsigned short* __restrict__ kh,
                                                unsigned short* __restrict__ vth,
                                                float2* __restrict__ qn2,
                                                float2* __restrict__ kn2) {
  const int qt = blockIdx.x, h = blockIdx.y, b = blockIdx.z;
  const int bh = b * NHEAD + h;
  const int tid = threadIdx.x;
  const int w = tid >> 6, lane = tid & 63;
  const float sc = sqrtf(cptr[0]);

  // phase 1: exp0 on q,k head-vectors of the 64 rows (128 vectors, 32 per wave)
  for (int t = 0; t < 32; ++t) {
    const int vv = w * 32 + t;        // 0..127
    const int which = vv & 1;
    const int r = vv >> 1;            // 0..63
    const int n = qt * 64 + r;
    const float v = qkv[((size_t)(b * SEQ + n)) * QKV_COLS + which * DIM + h * HEAD_DIM + lane];
    const float ss = wave_sum64(v * v);
    const float nn = fmaxf(sqrtf(ss), EPS_F);
    const float scn = sc * nn;
    const float f = tanhf(scn) / scn;
    (which ? kh : qh)[((size_t)bh * SEQ + n) * HEAD_DIM + lane] = f2bf(v * f);
    if (lane == 0) {
      const float nrm = ss * f * f;
      (which ? kn2 : qn2)[(size_t)bh * SEQ + n] =
          make_float2(nrm, 1.0f / (1.0f - fminf(nrm, 0.99f)));
    }
  }

  // phase 2: V transpose through LDS
  __shared__ unsigned short T[64 * PADK];
  const int r2 = tid >> 2;
  const int c0 = (tid & 3) << 4;
  const float* src = qkv + ((size_t)(b * SEQ + qt * 64 + r2)) * QKV_COLS + 2 * DIM + h * HEAD_DIM + c0;
#pragma unroll
  for (int z = 0; z < 16; z += 4) {
    const float4 v = *(const float4*)(src + z);
    T[(c0 + z + 0) * PADK + r2] = f2bf(v.x);
    T[(c0 + z + 1) * PADK + r2] = f2bf(v.y);
    T[(c0 + z + 2) * PADK + r2] = f2bf(v.z);
    T[(c0 + z + 3) * PADK + r2] = f2bf(v.w);
  }
  __syncthreads();
  const int d  = tid >> 2;
  const int k0 = (tid & 3) << 4;
  unsigned short* dst = vth + ((size_t)bh * HEAD_DIM + d) * SEQ + (size_t)qt * 64 + k0;
  *(uint4*)dst       = *(const uint4*)&T[d * PADK + k0];
  *(uint4*)(dst + 8) = *(const uint4*)&T[d * PADK + k0 + 8];
}

// ------------- MFMA flash attention, S^T form, w-direct softmax -------------
// block = (64-q tile, h, b); 4 waves x 16-query strips; 128-key staging rounds.
// S^T = K·Q^T so q-side scalars hoist (C row = key = quad*4+i, col = q = lq);
// Ps written packed (b64, 4 keys/lane); K/V via swizzled global_load_lds.
__global__ __launch_bounds__(256) void flash_mfma(const unsigned short* __restrict__ qh,
                                                  const unsigned short* __restrict__ kh,
                                                  const unsigned short* __restrict__ vth,
                                                  const float2* __restrict__ qn2,
                                                  const float2* __restrict__ kn2,
                                                  unsigned short* __restrict__ attn_out) {
  const int qt = blockIdx.x, h = blockIdx.y, b = blockIdx.z;
  const int bh = b * NHEAD + h;
  const int tid = threadIdx.x;
  const int w = tid >> 6, lane = tid & 63;
  const int lq = lane & 15, quad = lane >> 4;

  __shared__ unsigned short Ks[2 * 64 * 64];  // swizzled [key][hd], 2 sub-tiles
  __shared__ unsigned short Vt[2 * 64 * 64];  // swizzled [d][key], 2 sub-tiles
  __shared__ unsigned short Ps[64 * PADK];    // [q][key], stride 72
  __shared__ float knA[128], knB[128];        // norms / reciprocals for the 128 staged keys
  __shared__ float l_s[64];

  const unsigned short* qbase = qh + ((size_t)bh * SEQ + (size_t)qt * 64) * HEAD_DIM;
  const float2* qnb = qn2 + (size_t)bh * SEQ + (size_t)qt * 64;
  const float2* knb = kn2 + (size_t)bh * SEQ;

  const int srow = tid >> 3, spos = tid & 7;
  const int sB = spos ^ (srow & 7);
  const char* kgsrc = (const char*)(kh + (size_t)bh * SEQ * HEAD_DIM) + (size_t)srow * 128 + sB * 16;
  const char* vgsrc = (const char*)(vth + (size_t)bh * HEAD_DIM * SEQ) + (size_t)srow * 4096 + sB * 16;

  // Q fragments (B operand in S^T): frag[l][j] = Q[q = w*16+(l&15)][hd = khf*32+quad*8+j]
  bfrag aq[2];
#pragma unroll
  for (int khf = 0; khf < 2; ++khf)
    aq[khf] = *(const bfrag*)(qbase + (size_t)(w * 16 + lq) * HEAD_DIM + khf * 32 + quad * 8);

  const float2 qq = qnb[w * 16 + lq];
  const float qnS = qq.x;
  const float rqS = 2.0f * qq.y;

  f32x4 oacc[4];
#pragma unroll
  for (int d = 0; d < 4; ++d) oacc[d] = (f32x4){0.f, 0.f, 0.f, 0.f};
  float l = 0.0f;
  const int swz = lq & 7;

  for (int rd = 0; rd < SEQ / 128; ++rd) {
    __syncthreads();  // all waves done reading prev round's tiles
    gl_lds16(kgsrc,                (char*)Ks + w * 1024);
    gl_lds16(kgsrc + 4096,         (char*)Ks + 4096 + w * 1024);
    gl_lds16(kgsrc + 8192,         (char*)Ks + 8192 + w * 1024);
    gl_lds16(kgsrc + 12288,        (char*)Ks + 12288 + w * 1024);
    gl_lds16(vgsrc,                (char*)Vt + w * 1024);
    gl_lds16(vgsrc + 131072,       (char*)Vt + 4096 + w * 1024);
    gl_lds16(vgsrc + 128,          (char*)Vt + 8192 + w * 1024);
    gl_lds16(vgsrc + 131072 + 128, (char*)Vt + 12288 + w * 1024);
    if (tid < 128) {
      const float2 kv = knb[rd * 128 + tid];
      knA[tid] = kv.x;
      knB[tid] = kv.y;
    }
    kgsrc += 16384;  // 128 keys * 128B
    vgsrc += 256;    // 128 keys * 2B per row
    __syncthreads();  // tiles + norms ready

#pragma unroll
    for (int t = 0; t < 2; ++t) {
      const unsigned short* KsT = &Ks[t * 4096];
      const unsigned short* VtT = &Vt[t * 4096];

      // ---- S^T strip [64k x 16q] = K·Q^T via MFMA ----
      f32x4 s[4];
#pragma unroll
      for (int st = 0; st < 4; ++st) s[st] = (f32x4){0.f, 0.f, 0.f, 0.f};
#pragma unroll
      for (int khf = 0; khf < 2; ++khf)
#pragma unroll
        for (int st = 0; st < 4; ++st) {
          const bfrag ak = *(const bfrag*)&KsT[(st * 16 + lq) * 64 + (((khf << 2) + quad) ^ swz) * 8];
          s[st] = __builtin_amdgcn_mfma_f32_16x16x32_bf16(ak, aq[khf], s[st], 0, 0, 0);
        }

      // ---- w = (inner + sqrt(inner^2-1))^(-1/8); pack 4 keys -> b64; l from truncated ----
#pragma unroll
      for (int st = 0; st < 4; ++st) {
        const f32x4 kna = *(const f32x4*)&knA[t * 64 + st * 16 + quad * 4];
        const f32x4 knr = *(const f32x4*)&knB[t * 64 + st * 16 + quad * 4];
        unsigned u[4];
#pragma unroll
        for (int i = 0; i < 4; ++i) {
          float tt = fmaf(-2.0f, s[st][i], qnS + kna[i]);
          tt = fmaxf(tt, 0.0f);
          const float inner = fmaf(tt, rqS * knr[i], 1.0f);
          const float root = __builtin_amdgcn_sqrtf(fmaf(inner, inner, -1.0f));
          const float wgt = __builtin_amdgcn_exp2f(-0.125f * __builtin_amdgcn_logf(inner + root));
          u[i] = __float_as_uint(wgt);
          l += __uint_as_float(u[i] & 0xffff0000u);
        }
        uint2 pk;
        pk.x = (u[0] >> 16) | (u[1] & 0xffff0000u);
        pk.y = (u[2] >> 16) | (u[3] & 0xffff0000u);
        *(uint2*)&Ps[(w * 16 + lq) * PADK + st * 16 + quad * 4] = pk;
      }

      // ---- O += P·V (intra-wave Ps strip: DS ops in-order, no barrier) ----
#pragma unroll
      for (int khf = 0; khf < 2; ++khf) {
        const bfrag ap = *(const bfrag*)&Ps[(w * 16 + lq) * PADK + khf * 32 + quad * 8];
#pragma unroll
        for (int d = 0; d < 4; ++d) {
          const bfrag bv = *(const bfrag*)&VtT[(d * 16 + lq) * 64 + (((khf << 2) + quad) ^ swz) * 8];
          oacc[d] = __builtin_amdgcn_mfma_f32_16x16x32_bf16(ap, bv, oacc[d], 0, 0, 0);
        }
      }
    }
  }

  // ---- l lives at q=lq; reduce across quads, redistribute via LDS (intra-wave) ----
  l += __shfl_xor(l, 16, 64);
  l += __shfl_xor(l, 32, 64);
  if (quad == 0) l_s[w * 16 + lq] = l;
  float rl4[4];
#pragma unroll
  for (int i = 0; i < 4; ++i) rl4[i] = __builtin_amdgcn_rcpf(l_s[w * 16 + quad * 4 + i]);

  unsigned short* ob = attn_out + ((size_t)b * SEQ + (size_t)qt * 64 + w * 16) * DIM + h * HEAD_DIM;
#pragma unroll
  for (int d = 0; d < 4; ++d)
#pragma unroll
    for (int i = 0; i < 4; ++i)
      ob[(size_t)(quad * 4 + i) * DIM + d * 16 + lq] = f2bf(oacc[d][i] * rl4[i]);
}

extern "C" void kernel_launch(void* const* d_in, const int* in_sizes, int n_in,
                              void* d_out, int out_size, void* d_ws, size_t ws_size,
                              hipStream_t stream) {
  const float* x      = (const float*)d_in[0];
  const float* w_qkv  = (const float*)d_in[1];
  const float* w_proj = (const float*)d_in[2];
  const float* b_proj = (const float*)d_in[3];
  const float* curv   = (const float*)d_in[4];
  float* outp = (float*)d_out;

  float* ws = (float*)d_ws;
  // region A (1,572,864 f): v_tan_bf during GEMM1; attn_bf during GEMM2
  unsigned short* v_tan_bf = (unsigned short*)ws;
  unsigned short* attn_bf  = (unsigned short*)ws;
  // region B (9,437,184 f): qkv fp32; reused as v_out fp32 after flash
  float* qkv   = ws + 1572864;
  float* v_out = qkv;
  // region C: qh, kh, vth (bf16, 3,145,728 each)
  unsigned short* qh  = (unsigned short*)(qkv + 9437184);
  unsigned short* kh  = qh + 3145728;
  unsigned short* vth = kh + 3145728;
  // region D: weights bf16
  unsigned short* wqkv_bf  = vth + 3145728;
  unsigned short* wproj_bf = wqkv_bf + 1769472;
  // region E: (norm, reciprocal) pairs
  float2* qn2 = (float2*)(wproj_bf + 589824);
  float2* kn2 = qn2 + 49152;

  conv_bf16_2<<<dim3((2359296 / 4 + 255) / 256), dim3(256), 0, stream>>>(
      w_qkv, 1769472, w_proj, 589824, wqkv_bf, wproj_bf);
  log0_kernel<<<dim3(ROWS / 4), dim3(256), 0, stream>>>(x, curv, v_tan_bf);
  gemm_nt_mfma<<<dim3(QKV_COLS / 128, ROWS / 128), dim3(256), 0, stream>>>(
      v_tan_bf, wqkv_bf, qkv, ROWS, QKV_COLS, DIM, nullptr);
  qkv_prep<<<dim3(SEQ / 64, NHEAD, 2), dim3(256), 0, stream>>>(qkv, curv, qh, kh, vth,
                                                               qn2, kn2);
  flash_mfma<<<dim3(SEQ / 64, NHEAD, 2), dim3(256), 0, stream>>>(qh, kh, vth, qn2,
                                                                 kn2, attn_bf);
  gemm_nt_mfma<<<dim3(DIM / 128, ROWS / 128), dim3(256), 0, stream>>>(
      attn_bf, wproj_bf, v_out, ROWS, DIM, DIM, b_proj);
  exp0_out_kernel<<<dim3(ROWS / 4), dim3(256), 0, stream>>>(v_out, curv, outp);
}

// Round 6
// 227.100 us; speedup vs baseline: 4.2038x; 1.0324x over previous
//
#include <hip/hip_runtime.h>
#include <cmath>

#define ROWS 4096      // B*N
#define DIM 768        // D
#define QKV_COLS 2304  // 3*D
#define NHEAD 12
#define HEAD_DIM 64
#define SEQ 2048
#define PADK 72        // LDS row stride (bf16) for VALU-written tiles (Ps, transpose scratch)

static constexpr float SCALE_F = 0.125f;   // HD^-0.5
static constexpr float EPS_F   = 1e-8f;

typedef __bf16 bfrag __attribute__((ext_vector_type(8)));   // 8 bf16 = 4 VGPR (MFMA A/B frag)
typedef float  f32x4 __attribute__((ext_vector_type(4)));   // MFMA C/D frag

__device__ __forceinline__ float wave_sum64(float v) {
#pragma unroll
  for (int off = 1; off < 64; off <<= 1) v += __shfl_xor(v, off, 64);
  return v;
}

__device__ __forceinline__ unsigned short f2bf(float f) {
  unsigned u = __float_as_uint(f);
  u += 0x7fffu + ((u >> 16) & 1u);
  return (unsigned short)(u >> 16);
}

__device__ __forceinline__ void gl_lds16(const void* g, void* l) {
  __builtin_amdgcn_global_load_lds((const __attribute__((address_space(1))) void*)g,
                                   (__attribute__((address_space(3))) void*)l, 16, 0, 0);
}

// ---------------- f32 -> bf16 cast (both weight tensors, one launch) ----------------
__global__ __launch_bounds__(256) void conv_bf16_2(const float* __restrict__ a, int na,
                                                   const float* __restrict__ b, int nb,
                                                   unsigned short* __restrict__ da,
                                                   unsigned short* __restrict__ db) {
  const int i = (blockIdx.x * 256 + threadIdx.x) * 4;
  const float* s;
  unsigned short* d;
  int j;
  if (i < na) { s = a; d = da; j = i; }
  else { j = i - na; if (j >= nb) return; s = b; d = db; }
  const float4 v = *(const float4*)(s + j);
  ushort4 o;
  o.x = f2bf(v.x); o.y = f2bf(v.y); o.z = f2bf(v.z); o.w = f2bf(v.w);
  *(ushort4*)(d + j) = o;
}

// ---------------- log0 -> bf16 tangent vectors ----------------
__global__ __launch_bounds__(256) void log0_kernel(const float* __restrict__ x,
                                                   const float* __restrict__ cptr,
                                                   unsigned short* __restrict__ vout) {
  const int lane = threadIdx.x & 63;
  const int row  = (blockIdx.x << 2) + (threadIdx.x >> 6);
  const float* xr = x + (size_t)row * DIM;
  unsigned short* vr = vout + (size_t)row * DIM;
  float vals[12];
  float ss = 0.f;
#pragma unroll
  for (int i = 0; i < 12; ++i) {
    float t = xr[lane + (i << 6)];
    vals[i] = t;
    ss += t * t;
  }
  ss = wave_sum64(ss);
  const float sc  = sqrtf(cptr[0]);
  const float n   = fmaxf(sqrtf(ss), EPS_F);
  const float scn = sc * n;
  const float t   = fminf(scn, 1.0f - 1e-7f);
  const float f   = atanhf(t) / scn;
#pragma unroll
  for (int i = 0; i < 12; ++i) vr[lane + (i << 6)] = f2bf(vals[i] * f);
}

// ---------------- final exp0: out = tanh(sc*n) * v / (sc*n) ----------------
__global__ __launch_bounds__(256) void exp0_out_kernel(const float* __restrict__ vin,
                                                       const float* __restrict__ cptr,
                                                       float* __restrict__ outp) {
  const int lane = threadIdx.x & 63;
  const int row  = (blockIdx.x << 2) + (threadIdx.x >> 6);
  const float* vr = vin + (size_t)row * DIM;
  float* orow = outp + (size_t)row * DIM;
  float vals[12];
  float ss = 0.f;
#pragma unroll
  for (int i = 0; i < 12; ++i) {
    float t = vr[lane + (i << 6)];
    vals[i] = t;
    ss += t * t;
  }
  ss = wave_sum64(ss);
  const float sc  = sqrtf(cptr[0]);
  const float n   = fmaxf(sqrtf(ss), EPS_F);
  const float scn = sc * n;
  const float f   = tanhf(scn) / scn;
#pragma unroll
  for (int i = 0; i < 12; ++i) orow[lane + (i << 6)] = vals[i] * f;
}

// ---------------- MFMA GEMM NT, prefetch double-buffered ----------------
// BM x BN tile, BK=32, 4 waves (2x2), global_load_lds width=16 into alternating buffers;
// single barrier per K-iter: prefetch(k+1) issued right after it, overlaps compute(k).
template<int BM, int BN>
__global__ __launch_bounds__(256) void gemm_nt_dbuf(const unsigned short* __restrict__ A,
                                                    const unsigned short* __restrict__ B,
                                                    float* __restrict__ C,
                                                    int M, int Ncols, int K,
                                                    const float* __restrict__ bias) {
  constexpr int FI = BM / 32;   // A frags per wave
  constexpr int FJ = BN / 32;   // B frags per wave
  constexpr int CH = BM / 64;   // gl_lds insts per matrix per iter
  __shared__ unsigned short As[2][BM * 32];
  __shared__ unsigned short Bs[2][BN * 32];
  const int tid = threadIdx.x;
  const int w = tid >> 6, lane = tid & 63;
  const int lq = lane & 15, quad = lane >> 4;
  const int wr = w >> 1, wc = w & 1;
  const int row0 = blockIdx.y * BM;
  const int col0 = blockIdx.x * BN;
  const int srow  = lane >> 2;
  const int skoff = (lane & 3) << 3;

  f32x4 acc[FI][FJ];
#pragma unroll
  for (int i = 0; i < FI; ++i)
#pragma unroll
    for (int j = 0; j < FJ; ++j) acc[i][j] = (f32x4){0.f, 0.f, 0.f, 0.f};

  auto pf = [&](int k0, int buf) {
#pragma unroll
    for (int c = 0; c < CH; ++c) {
      const int r = c * 64 + w * 16;
      gl_lds16(A + (size_t)(row0 + r + srow) * K + k0 + skoff, &As[buf][r * 32]);
      gl_lds16(B + (size_t)(col0 + r + srow) * K + k0 + skoff, &Bs[buf][r * 32]);
    }
  };

  pf(0, 0);
  const int NIT = K / 32;
  for (int it = 0; it < NIT; ++it) {
    const int buf = it & 1;
    __syncthreads();               // drains prefetch(it) -> tiles ready; all waves done with buf^1
    if (it + 1 < NIT) pf((it + 1) * 32, buf ^ 1);

    bfrag af[FI], bfg[FJ];
#pragma unroll
    for (int i = 0; i < FI; ++i)
      af[i] = *(const bfrag*)&As[buf][(wr * (BM / 2) + i * 16 + lq) * 32 + (quad << 3)];
#pragma unroll
    for (int j = 0; j < FJ; ++j)
      bfg[j] = *(const bfrag*)&Bs[buf][(wc * (BN / 2) + j * 16 + lq) * 32 + (quad << 3)];
#pragma unroll
    for (int i = 0; i < FI; ++i)
#pragma unroll
      for (int j = 0; j < FJ; ++j)
        acc[i][j] = __builtin_amdgcn_mfma_f32_16x16x32_bf16(af[i], bfg[j], acc[i][j], 0, 0, 0);
  }

#pragma unroll
  for (int i = 0; i < FI; ++i) {
    const int crow = row0 + wr * (BM / 2) + i * 16 + (quad << 2);
#pragma unroll
    for (int j = 0; j < FJ; ++j) {
      const int col = col0 + wc * (BN / 2) + j * 16 + lq;
      const float bj = bias ? bias[col] : 0.0f;
      float* cp = C + (size_t)crow * Ncols + col;
#pragma unroll
      for (int r = 0; r < 4; ++r)
        cp[(size_t)r * Ncols] = acc[i][j][r] + bj;
    }
  }
}

// ------------- fused prep: exp0(q,k) -> bf16 head-major + norms; V -> bf16 transposed ----
__global__ __launch_bounds__(256) void qkv_prep(const float* __restrict__ qkv,
                                                const float* __restrict__ cptr,
                                                unsigned short* __restrict__ qh,
                                                unsigned short* __restrict__ kh,
                                                unsigned short* __restrict__ vth,
                                                float2* __restrict__ qn2,
                                                float2* __restrict__ kn2) {
  const int qt = blockIdx.x, h = blockIdx.y, b = blockIdx.z;
  const int bh = b * NHEAD + h;
  const int tid = threadIdx.x;
  const int w = tid >> 6, lane = tid & 63;
  const float sc = sqrtf(cptr[0]);

  for (int t = 0; t < 32; ++t) {
    const int vv = w * 32 + t;
    const int which = vv & 1;
    const int r = vv >> 1;
    const int n = qt * 64 + r;
    const float v = qkv[((size_t)(b * SEQ + n)) * QKV_COLS + which * DIM + h * HEAD_DIM + lane];
    const float ss = wave_sum64(v * v);
    const float nn = fmaxf(sqrtf(ss), EPS_F);
    const float scn = sc * nn;
    const float f = tanhf(scn) / scn;
    (which ? kh : qh)[((size_t)bh * SEQ + n) * HEAD_DIM + lane] = f2bf(v * f);
    if (lane == 0) {
      const float nrm = ss * f * f;
      (which ? kn2 : qn2)[(size_t)bh * SEQ + n] =
          make_float2(nrm, 1.0f / (1.0f - fminf(nrm, 0.99f)));
    }
  }

  __shared__ unsigned short T[64 * PADK];
  const int r2 = tid >> 2;
  const int c0 = (tid & 3) << 4;
  const float* src = qkv + ((size_t)(b * SEQ + qt * 64 + r2)) * QKV_COLS + 2 * DIM + h * HEAD_DIM + c0;
#pragma unroll
  for (int z = 0; z < 16; z += 4) {
    const float4 v = *(const float4*)(src + z);
    T[(c0 + z + 0) * PADK + r2] = f2bf(v.x);
    T[(c0 + z + 1) * PADK + r2] = f2bf(v.y);
    T[(c0 + z + 2) * PADK + r2] = f2bf(v.z);
    T[(c0 + z + 3) * PADK + r2] = f2bf(v.w);
  }
  __syncthreads();
  const int d  = tid >> 2;
  const int k0 = (tid & 3) << 4;
  unsigned short* dst = vth + ((size_t)bh * HEAD_DIM + d) * SEQ + (size_t)qt * 64 + k0;
  *(uint4*)dst       = *(const uint4*)&T[d * PADK + k0];
  *(uint4*)(dst + 8) = *(const uint4*)&T[d * PADK + k0 + 8];
}

// ------------- MFMA flash attention, S^T form, prefetch double-buffered -------------
// block = (64-q tile, h, b); 4 waves x 16-query strips; 64-key rounds, one barrier each;
// next round's K/V/kn prefetched into the alternate buffer right after the barrier.
__global__ __launch_bounds__(256) void flash_mfma(const unsigned short* __restrict__ qh,
                                                  const unsigned short* __restrict__ kh,
                                                  const unsigned short* __restrict__ vth,
                                                  const float2* __restrict__ qn2,
                                                  const float2* __restrict__ kn2,
                                                  unsigned short* __restrict__ attn_out) {
  const int qt = blockIdx.x, h = blockIdx.y, b = blockIdx.z;
  const int bh = b * NHEAD + h;
  const int tid = threadIdx.x;
  const int w = tid >> 6, lane = tid & 63;
  const int lq = lane & 15, quad = lane >> 4;

  __shared__ unsigned short Ks[2][64 * 64];  // swizzled [key][hd]
  __shared__ unsigned short Vt[2][64 * 64];  // swizzled [d][key]
  __shared__ unsigned short Ps[64 * PADK];   // [q][key], stride 72
  __shared__ float knA[2][64], knB[2][64];
  __shared__ float l_s[64];

  const unsigned short* qbase = qh + ((size_t)bh * SEQ + (size_t)qt * 64) * HEAD_DIM;
  const float2* qnb = qn2 + (size_t)bh * SEQ + (size_t)qt * 64;
  const float2* knb = kn2 + (size_t)bh * SEQ;

  const int srow = tid >> 3, spos = tid & 7;
  const int sB = spos ^ (srow & 7);
  const char* kgsrc = (const char*)(kh + (size_t)bh * SEQ * HEAD_DIM) + (size_t)srow * 128 + sB * 16;
  const char* vgsrc = (const char*)(vth + (size_t)bh * HEAD_DIM * SEQ) + (size_t)srow * 4096 + sB * 16;

  auto prefetch = [&](int kt, int buf) {
    const char* kp = kgsrc + (size_t)kt * 8192;  // 64 keys * 128B
    const char* vp = vgsrc + (size_t)kt * 128;   // 64 keys * 2B per d-row
    gl_lds16(kp,          (char*)Ks[buf] + w * 1024);
    gl_lds16(kp + 4096,   (char*)Ks[buf] + 4096 + w * 1024);
    gl_lds16(vp,          (char*)Vt[buf] + w * 1024);
    gl_lds16(vp + 131072, (char*)Vt[buf] + 4096 + w * 1024);
    if (tid < 64) {
      const float2 kv = knb[kt * 64 + tid];
      knA[buf][tid] = kv.x;
      knB[buf][tid] = kv.y;
    }
  };

  // Q fragments (B operand in S^T): frag[l][j] = Q[q = w*16+(l&15)][hd = khf*32+quad*8+j]
  bfrag aq[2];
#pragma unroll
  for (int khf = 0; khf < 2; ++khf)
    aq[khf] = *(const bfrag*)(qbase + (size_t)(w * 16 + lq) * HEAD_DIM + khf * 32 + quad * 8);

  const float2 qq = qnb[w * 16 + lq];
  const float qnS = qq.x;
  const float rqS = 2.0f * qq.y;

  f32x4 oacc[4];
#pragma unroll
  for (int d = 0; d < 4; ++d) oacc[d] = (f32x4){0.f, 0.f, 0.f, 0.f};
  float l = 0.0f;
  const int swz = lq & 7;

  prefetch(0, 0);
  for (int kt = 0; kt < SEQ / 64; ++kt) {
    const int buf = kt & 1;
    __syncthreads();  // drains prefetch(kt): tiles[buf] ready; all waves done with buf^1
    if (kt + 1 < SEQ / 64) prefetch(kt + 1, buf ^ 1);

    // ---- S^T strip [64k x 16q] = K·Q^T via MFMA ----
    f32x4 s[4];
#pragma unroll
    for (int st = 0; st < 4; ++st) s[st] = (f32x4){0.f, 0.f, 0.f, 0.f};
#pragma unroll
    for (int khf = 0; khf < 2; ++khf)
#pragma unroll
      for (int st = 0; st < 4; ++st) {
        const bfrag ak = *(const bfrag*)&Ks[buf][(st * 16 + lq) * 64 + (((khf << 2) + quad) ^ swz) * 8];
        s[st] = __builtin_amdgcn_mfma_f32_16x16x32_bf16(ak, aq[khf], s[st], 0, 0, 0);
      }

    // ---- w = (inner + sqrt(inner^2-1))^(-1/8); pack 4 keys via v_perm; l from truncated ----
#pragma unroll
    for (int st = 0; st < 4; ++st) {
      const f32x4 kna = *(const f32x4*)&knA[buf][st * 16 + quad * 4];
      const f32x4 knr = *(const f32x4*)&knB[buf][st * 16 + quad * 4];
      unsigned u[4];
#pragma unroll
      for (int i = 0; i < 4; ++i) {
        float tt = fmaf(-2.0f, s[st][i], qnS + kna[i]);
        tt = fmaxf(tt, 0.0f);
        const float inner = fmaf(tt, rqS * knr[i], 1.0f);
        const float root = __builtin_amdgcn_sqrtf(fmaf(inner, inner, -1.0f));
        const float wgt = __builtin_amdgcn_exp2f(-0.125f * __builtin_amdgcn_logf(inner + root));
        u[i] = __float_as_uint(wgt);
        l += __uint_as_float(u[i] & 0xffff0000u);
      }
      uint2 pk;
      pk.x = __builtin_amdgcn_perm(u[1], u[0], 0x07060302u);
      pk.y = __builtin_amdgcn_perm(u[3], u[2], 0x07060302u);
      *(uint2*)&Ps[(w * 16 + lq) * PADK + st * 16 + quad * 4] = pk;
    }

    // ---- O += P·V (intra-wave Ps strip: DS ops in-order, no barrier) ----
#pragma unroll
    for (int khf = 0; khf < 2; ++khf) {
      const bfrag ap = *(const bfrag*)&Ps[(w * 16 + lq) * PADK + khf * 32 + quad * 8];
#pragma unroll
      for (int d = 0; d < 4; ++d) {
        const bfrag bv = *(const bfrag*)&Vt[buf][(d * 16 + lq) * 64 + (((khf << 2) + quad) ^ swz) * 8];
        oacc[d] = __builtin_amdgcn_mfma_f32_16x16x32_bf16(ap, bv, oacc[d], 0, 0, 0);
      }
    }
  }

  // ---- l lives at q=lq; reduce across quads, redistribute via LDS (intra-wave) ----
  l += __shfl_xor(l, 16, 64);
  l += __shfl_xor(l, 32, 64);
  if (quad == 0) l_s[w * 16 + lq] = l;
  float rl4[4];
#pragma unroll
  for (int i = 0; i < 4; ++i) rl4[i] = __builtin_amdgcn_rcpf(l_s[w * 16 + quad * 4 + i]);

  unsigned short* ob = attn_out + ((size_t)b * SEQ + (size_t)qt * 64 + w * 16) * DIM + h * HEAD_DIM;
#pragma unroll
  for (int d = 0; d < 4; ++d)
#pragma unroll
    for (int i = 0; i < 4; ++i)
      ob[(size_t)(quad * 4 + i) * DIM + d * 16 + lq] = f2bf(oacc[d][i] * rl4[i]);
}

extern "C" void kernel_launch(void* const* d_in, const int* in_sizes, int n_in,
                              void* d_out, int out_size, void* d_ws, size_t ws_size,
                              hipStream_t stream) {
  const float* x      = (const float*)d_in[0];
  const float* w_qkv  = (const float*)d_in[1];
  const float* w_proj = (const float*)d_in[2];
  const float* b_proj = (const float*)d_in[3];
  const float* curv   = (const float*)d_in[4];
  float* outp = (float*)d_out;

  float* ws = (float*)d_ws;
  // region A (1,572,864 f): v_tan_bf during GEMM1; attn_bf during GEMM2
  unsigned short* v_tan_bf = (unsigned short*)ws;
  unsigned short* attn_bf  = (unsigned short*)ws;
  // region B (9,437,184 f): qkv fp32; reused as v_out fp32 after flash
  float* qkv   = ws + 1572864;
  float* v_out = qkv;
  // region C: qh, kh, vth (bf16, 3,145,728 each)
  unsigned short* qh  = (unsigned short*)(qkv + 9437184);
  unsigned short* kh  = qh + 3145728;
  unsigned short* vth = kh + 3145728;
  // region D: weights bf16
  unsigned short* wqkv_bf  = vth + 3145728;
  unsigned short* wproj_bf = wqkv_bf + 1769472;
  // region E: (norm, reciprocal) pairs
  float2* qn2 = (float2*)(wproj_bf + 589824);
  float2* kn2 = qn2 + 49152;

  conv_bf16_2<<<dim3((2359296 / 4 + 255) / 256), dim3(256), 0, stream>>>(
      w_qkv, 1769472, w_proj, 589824, wqkv_bf, wproj_bf);
  log0_kernel<<<dim3(ROWS / 4), dim3(256), 0, stream>>>(x, curv, v_tan_bf);
  gemm_nt_dbuf<128, 128><<<dim3(QKV_COLS / 128, ROWS / 128), dim3(256), 0, stream>>>(
      v_tan_bf, wqkv_bf, qkv, ROWS, QKV_COLS, DIM, nullptr);
  qkv_prep<<<dim3(SEQ / 64, NHEAD, 2), dim3(256), 0, stream>>>(qkv, curv, qh, kh, vth,
                                                               qn2, kn2);
  flash_mfma<<<dim3(SEQ / 64, NHEAD, 2), dim3(256), 0, stream>>>(qh, kh, vth, qn2,
                                                                 kn2, attn_bf);
  gemm_nt_dbuf<64, 64><<<dim3(DIM / 64, ROWS / 64), dim3(256), 0, stream>>>(
      attn_bf, wproj_bf, v_out, ROWS, DIM, DIM, b_proj);
  exp0_out_kernel<<<dim3(ROWS / 4), dim3(256), 0, stream>>>(v_out, curv, outp);
}